// Round 1
// baseline (1231.743 us; speedup 1.0000x reference)
//
#include <hip/hip_runtime.h>
#include <hip/hip_fp16.h>
#include <cstddef>

// Problem constants (match reference)
#define N_NODES 100000
#define N_EDGES 1600000
#define E_TOT   (N_EDGES + N_NODES)   // edges + self loops = 1,700,000
#define IN_DIM  64
#define HIDDEN  128
#define Z_DIM   64

// Bucketed CSR build: BN consecutive dst nodes per bucket
#define BN 128
#define NB ((N_NODES + BN - 1) / BN)   // 782

// ---------------- CSR build (two-level counting sort) ----------------

__global__ __launch_bounds__(1024) void binit_k(int* __restrict__ bhist, int nb) {
    int t = threadIdx.x;
    if (t < nb) bhist[t] = 0;
}

// histogram real edges into NB dst-buckets (self loops synthesized later in csr_k)
__global__ __launch_bounds__(256) void bhist_k(const int* __restrict__ dst, int* __restrict__ bhist, int e) {
    int i = blockIdx.x * 256 + threadIdx.x;
    if (i < e) atomicAdd(&bhist[dst[i] >> 7], 1);
}

// single-block exclusive scan of NB (<=1024) bucket counts -> boff, bcur
__global__ __launch_bounds__(1024) void bscan_k(const int* __restrict__ bhist, int* __restrict__ boff,
                                                int* __restrict__ bcur, int nb, int e) {
    __shared__ int s[1024];
    int t = threadIdx.x;
    int v = (t < nb) ? bhist[t] : 0;
    s[t] = v;
    __syncthreads();
#pragma unroll
    for (int off = 1; off < 1024; off <<= 1) {
        int x = (t >= off) ? s[t - off] : 0;
        __syncthreads();
        s[t] += x;
        __syncthreads();
    }
    if (t < nb) {
        int ex = s[t] - v;
        boff[t] = ex;
        bcur[t] = ex;
    }
    if (t == 0) boff[nb] = e;
}

// scatter edges into bucket-contiguous storage, packed 4B: {local_dst(7b) << 17 | src(17b)}
__global__ __launch_bounds__(256) void bin_k(const int* __restrict__ src, const int* __restrict__ dst,
                                             int* __restrict__ bcur, int* __restrict__ binned, int e) {
    int i = blockIdx.x * 256 + threadIdx.x;
    if (i >= e) return;
    int s = src[i], d = dst[i];
    int p = atomicAdd(&bcur[d >> 7], 1);
    binned[p] = ((d & 127) << 17) | s;
}

// one block per bucket: LDS degree hist (+1 self loop) -> dinv + rowptr (via LDS scan,
// bucket em base = boff[b] + BN*b), then place edges with LDS cursors. All em writes for
// a bucket come from ONE CU -> full-line merge in its L2 (kills the 8x write blowup).
__global__ __launch_bounds__(256) void csr_k(const int* __restrict__ binned, const int* __restrict__ boff,
                                             int* __restrict__ rowptr, float* __restrict__ dinv,
                                             int* __restrict__ em, int n, int etot) {
    __shared__ int hist[BN];
    __shared__ int sc[BN];
    __shared__ int cur[BN];
    int b = blockIdx.x;
    int t = threadIdx.x;
    int n0 = b * BN;
    int nn = n - n0; if (nn > BN) nn = BN;
    int e0 = boff[b], e1 = boff[b + 1];

    if (t < BN) hist[t] = (t < nn) ? 1 : 0;   // self loop
    __syncthreads();
    for (int i = e0 + t; i < e1; i += 256)
        atomicAdd(&hist[binned[i] >> 17], 1);
    __syncthreads();

    int v = (t < BN) ? hist[t] : 0;
    if (t < BN) sc[t] = v;
    __syncthreads();
#pragma unroll
    for (int off = 1; off < BN; off <<= 1) {
        int x = (t < BN && t >= off) ? sc[t - off] : 0;
        __syncthreads();
        if (t < BN) sc[t] += x;
        __syncthreads();
    }

    int base = e0 + n0;                       // global em offset of this bucket
    if (t < nn) {
        int rp = sc[t] - v;                   // exclusive scan (local, incl self slots)
        int node = n0 + t;
        rowptr[node] = base + rp;
        dinv[node] = rsqrtf((float)v);        // v >= 1 always
        em[base + rp] = node;                 // self loop first
        cur[t] = rp + 1;
    }
    if (b == gridDim.x - 1 && t == 0) rowptr[n] = etot;
    __syncthreads();

    for (int i = e0 + t; i < e1; i += 256) {
        int pk = binned[i];
        int q = atomicAdd(&cur[pk >> 17], 1);
        em[base + q] = pk & 0x1FFFF;
    }
}

// cast fp32 -> fp16, 8 elems per thread (total must be divisible by 8)
__global__ __launch_bounds__(256) void cast16_k(const float* __restrict__ in, __half* __restrict__ out, int total8) {
    int i = blockIdx.x * 256 + threadIdx.x;
    if (i >= total8) return;
    const float4* in4 = (const float4*)in;
    float4 a = in4[2 * i], b = in4[2 * i + 1];
    __half2 h0 = __floats2half2_rn(a.x, a.y);
    __half2 h1 = __floats2half2_rn(a.z, a.w);
    __half2 h2 = __floats2half2_rn(b.x, b.y);
    __half2 h3 = __floats2half2_rn(b.z, b.w);
    uint4 pk = make_uint4(*(unsigned*)&h0, *(unsigned*)&h1, *(unsigned*)&h2, *(unsigned*)&h3);
    ((uint4*)out)[i] = pk;
}

// ---------------- Aggregation (gather): fp16 rows, fp32 accumulate ----------------
// em entry is now just src (4B); weight recomputed as dinv[src]*dinv[node] from the
// cache-resident 400KB dinv array. Row = DIM*2 bytes. Lane loads 16B (8 halves):
// DIM=128 -> 16 lanes/row, DIM=64 -> 8 lanes/row. 4 loads in flight per iter.
// OOB edges clamp-indexed with weight 0 (beg<end always: self-loop).

template <int DIM>
__global__ __launch_bounds__(256) void agg_k(const __half* __restrict__ H, const int* __restrict__ rowptr,
                                             const int* __restrict__ em, const float* __restrict__ dinv,
                                             float* __restrict__ out, int n) {
    int node = (int)((blockIdx.x * 256 + threadIdx.x) >> 6);
    if (node >= n) return;
    int lane = threadIdx.x & 63;
    int beg = rowptr[node], end = rowptr[node + 1];
    float dn = dinv[node];
    const uint4* H4 = (const uint4*)H;       // 8 halves per uint4

    constexpr int RV   = DIM / 8;            // 16B-chunks per row (128->16, 64->8)
    constexpr int SUBS = 64 / RV;            // edges per load instr (4 or 8)
    int sub = lane / RV;
    int fl  = lane % RV;

    float acc[8];
#pragma unroll
    for (int q = 0; q < 8; q++) acc[q] = 0.f;

    for (int j = beg; j < end; j += SUBS * 4) {
        int   s[4]; float w[4];
#pragma unroll
        for (int p = 0; p < 4; p++) {
            int idx = j + SUBS * p + sub;
            int ci  = idx < end ? idx : beg;
            int sv  = em[ci];
            s[p] = sv;
            w[p] = idx < end ? dinv[sv] * dn : 0.f;
        }
#pragma unroll
        for (int p = 0; p < 4; p++) {
            uint4 v = H4[(size_t)s[p] * RV + fl];
            const __half2* hp = (const __half2*)&v;
            float2 f0 = __half22float2(hp[0]);
            float2 f1 = __half22float2(hp[1]);
            float2 f2 = __half22float2(hp[2]);
            float2 f3 = __half22float2(hp[3]);
            acc[0] += w[p] * f0.x; acc[1] += w[p] * f0.y;
            acc[2] += w[p] * f1.x; acc[3] += w[p] * f1.y;
            acc[4] += w[p] * f2.x; acc[5] += w[p] * f2.y;
            acc[6] += w[p] * f3.x; acc[7] += w[p] * f3.y;
        }
    }
    // combine sub-waves: xor-reduce down to sub==0
#pragma unroll
    for (int off = 32; off >= RV; off >>= 1) {
#pragma unroll
        for (int q = 0; q < 8; q++) acc[q] += __shfl_xor(acc[q], off);
    }
    if (sub == 0) {
        float* op = out + (size_t)node * DIM + fl * 8;
        float4 v0 = make_float4(acc[0], acc[1], acc[2], acc[3]);
        float4 v1 = make_float4(acc[4], acc[5], acc[6], acc[7]);
        *(float4*)op = v0;
        *(float4*)(op + 4) = v1;
    }
}

// ---------------- Dense layer: whole W in LDS, ONE barrier, A streamed from global --------
// Block = 256 threads, 128 nodes. fg=t&7 owns feats fg*4+32*j; mg=t>>3 owns rows mg*4+r.
// OUTT=__half: hidden layers emit fp16 rows for the next gather; OUTT=float: head GEMM
// emits fp32. DUAL: cols 0..63 -> Ca (mu), 64..127 -> Cb.

template <int K, bool RELU, bool DUAL, typename OUTT>
__global__ __launch_bounds__(256, 3) void gemm128_k(const float* __restrict__ A,
                                                    const float* __restrict__ Wa, const float* __restrict__ Wb,
                                                    const float* __restrict__ ba, const float* __restrict__ bb,
                                                    OUTT* __restrict__ Ca, OUTT* __restrict__ Cb, int n) {
    constexpr int F  = 128;
    constexpr int NT = 128;          // nodes per block
    __shared__ __align__(16) float Ws[K * F];    // 32 KB (K=64) / 64 KB (K=128)

    int t  = threadIdx.x;
    int fg = t & 7;
    int mg = t >> 3;
    int m0 = blockIdx.x * NT;

    // stage whole W (K*F/4 float4, coalesced)
    for (int e = t; e < K * F / 4; e += 256) {
        float4 w;
        if (!DUAL) {
            w = ((const float4*)Wa)[e];
        } else {
            int r = e >> 5;              // k row
            int c = (e & 31) * 4;        // float col 0..127
            w = (c < 64) ? *(const float4*)&Wa[(size_t)r * 64 + c]
                         : *(const float4*)&Wb[(size_t)r * 64 + (c - 64)];
        }
        ((float4*)Ws)[e] = w;
    }
    __syncthreads();

    // row pointers (clamped; garbage rows computed but not stored)
    const float* Ap[4];
#pragma unroll
    for (int r = 0; r < 4; r++) {
        int row = m0 + mg * 4 + r;
        Ap[r] = A + (size_t)(row < n ? row : (n - 1)) * K;
    }

    float4 acc[4][4];                // [r][j]
#pragma unroll
    for (int r = 0; r < 4; r++)
#pragma unroll
        for (int j = 0; j < 4; j++) { acc[r][j].x = 0.f; acc[r][j].y = 0.f; acc[r][j].z = 0.f; acc[r][j].w = 0.f; }

    for (int k4 = 0; k4 < K; k4 += 4) {
        float4 av[4];
#pragma unroll
        for (int r = 0; r < 4; r++) av[r] = *(const float4*)&Ap[r][k4];
#pragma unroll
        for (int kk = 0; kk < 4; kk++) {
            float a0 = ((const float*)&av[0])[kk];
            float a1 = ((const float*)&av[1])[kk];
            float a2 = ((const float*)&av[2])[kk];
            float a3 = ((const float*)&av[3])[kk];
#pragma unroll
            for (int j = 0; j < 4; j++) {
                float4 w = ((const float4*)Ws)[(k4 + kk) * (F / 4) + fg + 8 * j];
                acc[0][j].x += a0 * w.x; acc[0][j].y += a0 * w.y; acc[0][j].z += a0 * w.z; acc[0][j].w += a0 * w.w;
                acc[1][j].x += a1 * w.x; acc[1][j].y += a1 * w.y; acc[1][j].z += a1 * w.z; acc[1][j].w += a1 * w.w;
                acc[2][j].x += a2 * w.x; acc[2][j].y += a2 * w.y; acc[2][j].z += a2 * w.z; acc[2][j].w += a2 * w.w;
                acc[3][j].x += a3 * w.x; acc[3][j].y += a3 * w.y; acc[3][j].z += a3 * w.z; acc[3][j].w += a3 * w.w;
            }
        }
    }

    // epilogue: bias + optional relu; DUAL splits cols 0..63 / 64..127
#pragma unroll
    for (int r = 0; r < 4; r++) {
        int node = m0 + mg * 4 + r;
        if (node >= n) break;
#pragma unroll
        for (int j = 0; j < 4; j++) {
            int f = fg * 4 + 32 * j;
            float4 v = acc[r][j];
            const float* bp;
            OUTT* cp;
            int fo;
            if (!DUAL) {
                bp = ba; cp = Ca + (size_t)node * F; fo = f;
            } else if (j < 2) {              // f < 64
                bp = ba; cp = Ca + (size_t)node * 64; fo = f;
            } else {
                bp = bb; cp = Cb + (size_t)node * 64; fo = f - 64;
            }
            v.x += bp[fo + 0]; v.y += bp[fo + 1]; v.z += bp[fo + 2]; v.w += bp[fo + 3];
            if (RELU) {
                v.x = fmaxf(v.x, 0.f); v.y = fmaxf(v.y, 0.f);
                v.z = fmaxf(v.z, 0.f); v.w = fmaxf(v.w, 0.f);
            }
            if constexpr (sizeof(OUTT) == 2) {
                __half2 p01 = __floats2half2_rn(v.x, v.y);
                __half2 p23 = __floats2half2_rn(v.z, v.w);
                uint2 pk = make_uint2(*(unsigned*)&p01, *(unsigned*)&p23);
                *(uint2*)&cp[fo] = pk;       // 8B fp16 store
            } else {
                *(float4*)&cp[fo] = v;
            }
        }
    }
}

// ---------------- launch ----------------

extern "C" void kernel_launch(void* const* d_in, const int* in_sizes, int n_in,
                              void* d_out, int out_size, void* d_ws, size_t ws_size,
                              hipStream_t stream) {
    const int N = N_NODES, E = N_EDGES, ETOT = E_TOT;

    const float* x    = (const float*)d_in[0];
    const int*   ei   = (const int*)d_in[1];
    const int*   srcA = ei;
    const int*   dstA = ei + E;
    const float* W1   = (const float*)d_in[2];
    const float* b1   = (const float*)d_in[3];
    const float* W2   = (const float*)d_in[4];
    const float* b2   = (const float*)d_in[5];
    const float* Wmu  = (const float*)d_in[6];
    const float* bmu  = (const float*)d_in[7];
    const float* Wlv  = (const float*)d_in[8];
    const float* blv  = (const float*)d_in[9];
    float* out = (float*)d_out;

    // workspace carve-out
    char* ws = (char*)d_ws;
    size_t o = 0;
    auto alloc = [&](size_t bytes) -> void* {
        o = (o + 255) & ~(size_t)255;
        void* p = ws + o;
        o += bytes;
        return p;
    };
    int*    bhist  = (int*)alloc((size_t)(NB + 1) * 4);
    int*    boff   = (int*)alloc((size_t)(NB + 1) * 4);
    int*    bcur   = (int*)alloc((size_t)(NB + 1) * 4);
    int*    binned = (int*)alloc((size_t)E * 4);          // packed {ldst, src}
    int*    rowptr = (int*)alloc((size_t)(N + 1) * 4);
    float*  dinv   = (float*)alloc((size_t)N * 4);
    int*    em     = (int*)alloc((size_t)ETOT * 4);       // src only
    float*  agg    = (float*)alloc((size_t)N * HIDDEN * 4);
    __half* x16    = (__half*)alloc((size_t)N * IN_DIM * 2);
    __half* h16    = (__half*)alloc((size_t)N * HIDDEN * 2);
    (void)ws_size;

    const int gE = (E + 255) / 256;          // 6250
    const int gAgg = (N + 3) / 4;            // 25000 (4 nodes/block)
    const int gGemm = (N + 127) / 128;       // 782
    const int gCast = (N * IN_DIM / 8 + 255) / 256;

    // CSR build (bucketed counting sort) + x cast
    binit_k<<<1, 1024, 0, stream>>>(bhist, NB);
    bhist_k<<<gE, 256, 0, stream>>>(dstA, bhist, E);
    bscan_k<<<1, 1024, 0, stream>>>(bhist, boff, bcur, NB, E);
    bin_k<<<gE, 256, 0, stream>>>(srcA, dstA, bcur, binned, E);
    csr_k<<<NB, 256, 0, stream>>>(binned, boff, rowptr, dinv, em, N, ETOT);
    cast16_k<<<gCast, 256, 0, stream>>>(x, x16, N * IN_DIM / 8);

    // layer 1: h16 = fp16(relu(Agg(x16) @ W1 + b1))   (aggregate in 64-dim)
    agg_k<64><<<gAgg, 256, 0, stream>>>(x16, rowptr, em, dinv, agg, N);
    gemm128_k<64, true, false, __half><<<gGemm, 256, 0, stream>>>(agg, W1, nullptr, b1, nullptr,
                                                                  h16, nullptr, N);

    // layer 2: h16 = fp16(relu(Agg(h16) @ W2 + b2))
    agg_k<128><<<gAgg, 256, 0, stream>>>(h16, rowptr, em, dinv, agg, N);
    gemm128_k<128, true, false, __half><<<gGemm, 256, 0, stream>>>(agg, W2, nullptr, b2, nullptr,
                                                                   h16, nullptr, N);

    // heads: aggregate once, ONE fused GEMM (cols 0..63 = mu, 64..127 = logvar), fp32 out
    agg_k<128><<<gAgg, 256, 0, stream>>>(h16, rowptr, em, dinv, agg, N);
    gemm128_k<128, false, true, float><<<gGemm, 256, 0, stream>>>(agg, Wmu, Wlv, bmu, blv,
                                                                  out, out + (size_t)N * Z_DIM, N);
}

// Round 2
// 570.615 us; speedup vs baseline: 2.1586x; 2.1586x over previous
//
#include <hip/hip_runtime.h>
#include <hip/hip_fp16.h>
#include <cstddef>

// Problem constants (match reference)
#define N_NODES 100000
#define N_EDGES 1600000
#define E_TOT   (N_EDGES + N_NODES)   // edges + self loops = 1,700,000
#define IN_DIM  64
#define HIDDEN  128
#define Z_DIM   64

// dst-buckets for locality-preserving fill
#define BN 128
#define NB ((N_NODES + BN - 1) / BN)   // 782
#define NBLK 256                        // chunk blocks for binA

// ---------------- CSR build ----------------

__global__ __launch_bounds__(256) void init_cnt_k(int* cnt, int n) {
    int i = blockIdx.x * 256 + threadIdx.x;
    if (i < n) cnt[i] = 1;   // self loop
}

// per-node degree count: 1.6M fire-and-forget atomics over 100K addresses (proven cheap)
__global__ __launch_bounds__(256) void count_k(const int* __restrict__ dst, int* cnt, int e) {
    int i = blockIdx.x * 256 + threadIdx.x;
    if (i < e) atomicAdd(&cnt[dst[i]], 1);
}

// block-level exclusive scan of cnt -> rowptr (+ per-block sums); also emits dinv = rsqrt(deg)
__global__ __launch_bounds__(256) void scan_block_k(const int* __restrict__ cnt, int* __restrict__ rowptr,
                                                    int* __restrict__ bsum, float* __restrict__ dinv, int n) {
    __shared__ int s[256];
    int tid = threadIdx.x;
    int i = blockIdx.x * 256 + tid;
    int v = (i < n) ? cnt[i] : 0;
    if (i < n) dinv[i] = rsqrtf((float)v);    // v >= 1 always (self loop)
    s[tid] = v;
    __syncthreads();
#pragma unroll
    for (int off = 1; off < 256; off <<= 1) {
        int t = (tid >= off) ? s[tid - off] : 0;
        __syncthreads();
        s[tid] += t;
        __syncthreads();
    }
    if (i < n) rowptr[i] = s[tid] - v;        // exclusive within block
    if (tid == 255) bsum[blockIdx.x] = s[255];
}

__global__ __launch_bounds__(512) void scan_bsum_k(int* bsum, int nb) {
    __shared__ int s[512];
    int tid = threadIdx.x;
    int v = (tid < nb) ? bsum[tid] : 0;
    s[tid] = v;
    __syncthreads();
#pragma unroll
    for (int off = 1; off < 512; off <<= 1) {
        int t = (tid >= off) ? s[tid - off] : 0;
        __syncthreads();
        s[tid] += t;
        __syncthreads();
    }
    if (tid < nb) bsum[tid] = s[tid] - v;     // exclusive
}

__global__ __launch_bounds__(256) void scan_add_k(int* __restrict__ rowptr, const int* __restrict__ bsum,
                                                  int n, int etot) {
    int i = blockIdx.x * 256 + threadIdx.x;
    if (i < n) rowptr[i] += bsum[blockIdx.x];
    if (i == 0) rowptr[n] = etot;
}

// bucket edge-space bases from rowptr: ebase[b] = rowptr[b*BN] - b*BN (removes self-loop slots)
__global__ __launch_bounds__(1024) void init_ebase_k(const int* __restrict__ rowptr,
                                                     int* __restrict__ ebase, int* __restrict__ bcur,
                                                     int e) {
    int b = threadIdx.x;
    if (b < NB) {
        int v = rowptr[b * BN] - b * BN;
        ebase[b] = v;
        bcur[b] = v;
    }
    if (b == 0) ebase[NB] = e;
}

// Phase A: chunked binning. Each block owns a contiguous edge chunk; LDS bucket-hist;
// ONE global with-return atomic per (block,bucket) to reserve a range (200K total, vs
// 1.6M per-edge — kills the contention stall); place chunk into bucket-contiguous
// binned[] via LDS cursors. Packed 4B: {local_dst(7b) << 17 | src(17b)}.
__global__ __launch_bounds__(256) void binA_k(const int* __restrict__ src, const int* __restrict__ dst,
                                              int* __restrict__ bcur, int* __restrict__ binned, int e) {
    __shared__ int hist[NB];
    __shared__ int cur[NB];
    int t = threadIdx.x;
    int ch = (e + gridDim.x - 1) / gridDim.x;
    int i0 = blockIdx.x * ch;
    int i1 = i0 + ch; if (i1 > e) i1 = e;

    for (int b = t; b < NB; b += 256) hist[b] = 0;
    __syncthreads();
    for (int i = i0 + t; i < i1; i += 256)
        atomicAdd(&hist[dst[i] >> 7], 1);
    __syncthreads();
    for (int b = t; b < NB; b += 256) {
        int h = hist[b];
        cur[b] = h ? atomicAdd(&bcur[b], h) : 0;
    }
    __syncthreads();
    for (int i = i0 + t; i < i1; i += 256) {
        int s = src[i], d = dst[i];
        int p = atomicAdd(&cur[d >> 7], 1);
        binned[p] = ((d & 127) << 17) | s;
    }
}

// Phase B: one block per bucket. Per-node LDS cursors seeded from rowptr; all em writes
// for the bucket's ~9KB region come from ONE CU -> full-line merge in its L2.
__global__ __launch_bounds__(256) void place_k(const int* __restrict__ binned, const int* __restrict__ ebase,
                                               const int* __restrict__ rowptr, int* __restrict__ em, int n) {
    __shared__ int cur[BN];
    int b = blockIdx.x, t = threadIdx.x;
    int n0 = b * BN;
    int nn = n - n0; if (nn > BN) nn = BN;
    if (t < nn) {
        int rp = rowptr[n0 + t];
        em[rp] = n0 + t;          // self loop first
        cur[t] = rp + 1;
    }
    __syncthreads();
    int e0 = ebase[b], e1 = ebase[b + 1];
    for (int i = e0 + t; i < e1; i += 256) {
        int pk = binned[i];
        int q = atomicAdd(&cur[pk >> 17], 1);
        em[q] = pk & 0x1FFFF;
    }
}

// cast fp32 -> fp16, 8 elems per thread (total must be divisible by 8)
__global__ __launch_bounds__(256) void cast16_k(const float* __restrict__ in, __half* __restrict__ out, int total8) {
    int i = blockIdx.x * 256 + threadIdx.x;
    if (i >= total8) return;
    const float4* in4 = (const float4*)in;
    float4 a = in4[2 * i], b = in4[2 * i + 1];
    __half2 h0 = __floats2half2_rn(a.x, a.y);
    __half2 h1 = __floats2half2_rn(a.z, a.w);
    __half2 h2 = __floats2half2_rn(b.x, b.y);
    __half2 h3 = __floats2half2_rn(b.z, b.w);
    uint4 pk = make_uint4(*(unsigned*)&h0, *(unsigned*)&h1, *(unsigned*)&h2, *(unsigned*)&h3);
    ((uint4*)out)[i] = pk;
}

// ---------------- Aggregation (gather): fp16 rows, fp32 accumulate ----------------
// em entry is src only (4B); weight = dinv[src]*dinv[node], dinv is 400KB cache-resident.
// Row = DIM*2 bytes. Lane loads 16B (8 halves): DIM=128 -> 16 lanes/row, DIM=64 -> 8
// lanes/row. 4 loads in flight per iter. OOB edges clamp-indexed with weight 0.

template <int DIM>
__global__ __launch_bounds__(256) void agg_k(const __half* __restrict__ H, const int* __restrict__ rowptr,
                                             const int* __restrict__ em, const float* __restrict__ dinv,
                                             float* __restrict__ out, int n) {
    int node = (int)((blockIdx.x * 256 + threadIdx.x) >> 6);
    if (node >= n) return;
    int lane = threadIdx.x & 63;
    int beg = rowptr[node], end = rowptr[node + 1];
    float dn = dinv[node];
    const uint4* H4 = (const uint4*)H;       // 8 halves per uint4

    constexpr int RV   = DIM / 8;            // 16B-chunks per row (128->16, 64->8)
    constexpr int SUBS = 64 / RV;            // edges per load instr (4 or 8)
    int sub = lane / RV;
    int fl  = lane % RV;

    float acc[8];
#pragma unroll
    for (int q = 0; q < 8; q++) acc[q] = 0.f;

    for (int j = beg; j < end; j += SUBS * 4) {
        int   s[4]; float w[4];
#pragma unroll
        for (int p = 0; p < 4; p++) {
            int idx = j + SUBS * p + sub;
            int ci  = idx < end ? idx : beg;
            int sv  = em[ci];
            s[p] = sv;
            w[p] = idx < end ? dinv[sv] * dn : 0.f;
        }
#pragma unroll
        for (int p = 0; p < 4; p++) {
            uint4 v = H4[(size_t)s[p] * RV + fl];
            const __half2* hp = (const __half2*)&v;
            float2 f0 = __half22float2(hp[0]);
            float2 f1 = __half22float2(hp[1]);
            float2 f2 = __half22float2(hp[2]);
            float2 f3 = __half22float2(hp[3]);
            acc[0] += w[p] * f0.x; acc[1] += w[p] * f0.y;
            acc[2] += w[p] * f1.x; acc[3] += w[p] * f1.y;
            acc[4] += w[p] * f2.x; acc[5] += w[p] * f2.y;
            acc[6] += w[p] * f3.x; acc[7] += w[p] * f3.y;
        }
    }
    // combine sub-waves: xor-reduce down to sub==0
#pragma unroll
    for (int off = 32; off >= RV; off >>= 1) {
#pragma unroll
        for (int q = 0; q < 8; q++) acc[q] += __shfl_xor(acc[q], off);
    }
    if (sub == 0) {
        float* op = out + (size_t)node * DIM + fl * 8;
        float4 v0 = make_float4(acc[0], acc[1], acc[2], acc[3]);
        float4 v1 = make_float4(acc[4], acc[5], acc[6], acc[7]);
        *(float4*)op = v0;
        *(float4*)(op + 4) = v1;
    }
}

// ---------------- Dense layer: whole W in LDS, ONE barrier, A streamed from global --------
// Block = 256 threads, 128 nodes. fg=t&7 owns feats fg*4+32*j; mg=t>>3 owns rows mg*4+r.
// OUTT=__half: hidden layers emit fp16 rows for the next gather; OUTT=float: head GEMM
// emits fp32. DUAL: cols 0..63 -> Ca (mu), 64..127 -> Cb.

template <int K, bool RELU, bool DUAL, typename OUTT>
__global__ __launch_bounds__(256, 3) void gemm128_k(const float* __restrict__ A,
                                                    const float* __restrict__ Wa, const float* __restrict__ Wb,
                                                    const float* __restrict__ ba, const float* __restrict__ bb,
                                                    OUTT* __restrict__ Ca, OUTT* __restrict__ Cb, int n) {
    constexpr int F  = 128;
    constexpr int NT = 128;          // nodes per block
    __shared__ __align__(16) float Ws[K * F];    // 32 KB (K=64) / 64 KB (K=128)

    int t  = threadIdx.x;
    int fg = t & 7;
    int mg = t >> 3;
    int m0 = blockIdx.x * NT;

    // stage whole W (K*F/4 float4, coalesced)
    for (int e = t; e < K * F / 4; e += 256) {
        float4 w;
        if (!DUAL) {
            w = ((const float4*)Wa)[e];
        } else {
            int r = e >> 5;              // k row
            int c = (e & 31) * 4;        // float col 0..127
            w = (c < 64) ? *(const float4*)&Wa[(size_t)r * 64 + c]
                         : *(const float4*)&Wb[(size_t)r * 64 + (c - 64)];
        }
        ((float4*)Ws)[e] = w;
    }
    __syncthreads();

    // row pointers (clamped; garbage rows computed but not stored)
    const float* Ap[4];
#pragma unroll
    for (int r = 0; r < 4; r++) {
        int row = m0 + mg * 4 + r;
        Ap[r] = A + (size_t)(row < n ? row : (n - 1)) * K;
    }

    float4 acc[4][4];                // [r][j]
#pragma unroll
    for (int r = 0; r < 4; r++)
#pragma unroll
        for (int j = 0; j < 4; j++) { acc[r][j].x = 0.f; acc[r][j].y = 0.f; acc[r][j].z = 0.f; acc[r][j].w = 0.f; }

    for (int k4 = 0; k4 < K; k4 += 4) {
        float4 av[4];
#pragma unroll
        for (int r = 0; r < 4; r++) av[r] = *(const float4*)&Ap[r][k4];
#pragma unroll
        for (int kk = 0; kk < 4; kk++) {
            float a0 = ((const float*)&av[0])[kk];
            float a1 = ((const float*)&av[1])[kk];
            float a2 = ((const float*)&av[2])[kk];
            float a3 = ((const float*)&av[3])[kk];
#pragma unroll
            for (int j = 0; j < 4; j++) {
                float4 w = ((const float4*)Ws)[(k4 + kk) * (F / 4) + fg + 8 * j];
                acc[0][j].x += a0 * w.x; acc[0][j].y += a0 * w.y; acc[0][j].z += a0 * w.z; acc[0][j].w += a0 * w.w;
                acc[1][j].x += a1 * w.x; acc[1][j].y += a1 * w.y; acc[1][j].z += a1 * w.z; acc[1][j].w += a1 * w.w;
                acc[2][j].x += a2 * w.x; acc[2][j].y += a2 * w.y; acc[2][j].z += a2 * w.z; acc[2][j].w += a2 * w.w;
                acc[3][j].x += a3 * w.x; acc[3][j].y += a3 * w.y; acc[3][j].z += a3 * w.z; acc[3][j].w += a3 * w.w;
            }
        }
    }

    // epilogue: bias + optional relu; DUAL splits cols 0..63 / 64..127
#pragma unroll
    for (int r = 0; r < 4; r++) {
        int node = m0 + mg * 4 + r;
        if (node >= n) break;
#pragma unroll
        for (int j = 0; j < 4; j++) {
            int f = fg * 4 + 32 * j;
            float4 v = acc[r][j];
            const float* bp;
            OUTT* cp;
            int fo;
            if (!DUAL) {
                bp = ba; cp = Ca + (size_t)node * F; fo = f;
            } else if (j < 2) {              // f < 64
                bp = ba; cp = Ca + (size_t)node * 64; fo = f;
            } else {
                bp = bb; cp = Cb + (size_t)node * 64; fo = f - 64;
            }
            v.x += bp[fo + 0]; v.y += bp[fo + 1]; v.z += bp[fo + 2]; v.w += bp[fo + 3];
            if (RELU) {
                v.x = fmaxf(v.x, 0.f); v.y = fmaxf(v.y, 0.f);
                v.z = fmaxf(v.z, 0.f); v.w = fmaxf(v.w, 0.f);
            }
            if constexpr (sizeof(OUTT) == 2) {
                __half2 p01 = __floats2half2_rn(v.x, v.y);
                __half2 p23 = __floats2half2_rn(v.z, v.w);
                uint2 pk = make_uint2(*(unsigned*)&p01, *(unsigned*)&p23);
                *(uint2*)&cp[fo] = pk;       // 8B fp16 store
            } else {
                *(float4*)&cp[fo] = v;
            }
        }
    }
}

// ---------------- launch ----------------

extern "C" void kernel_launch(void* const* d_in, const int* in_sizes, int n_in,
                              void* d_out, int out_size, void* d_ws, size_t ws_size,
                              hipStream_t stream) {
    const int N = N_NODES, E = N_EDGES, ETOT = E_TOT;

    const float* x    = (const float*)d_in[0];
    const int*   ei   = (const int*)d_in[1];
    const int*   srcA = ei;
    const int*   dstA = ei + E;
    const float* W1   = (const float*)d_in[2];
    const float* b1   = (const float*)d_in[3];
    const float* W2   = (const float*)d_in[4];
    const float* b2   = (const float*)d_in[5];
    const float* Wmu  = (const float*)d_in[6];
    const float* bmu  = (const float*)d_in[7];
    const float* Wlv  = (const float*)d_in[8];
    const float* blv  = (const float*)d_in[9];
    float* out = (float*)d_out;

    // workspace carve-out
    char* ws = (char*)d_ws;
    size_t o = 0;
    auto alloc = [&](size_t bytes) -> void* {
        o = (o + 255) & ~(size_t)255;
        void* p = ws + o;
        o += bytes;
        return p;
    };
    int*    cnt    = (int*)alloc((size_t)N * 4);
    int*    rowptr = (int*)alloc((size_t)(N + 1) * 4);
    float*  dinv   = (float*)alloc((size_t)N * 4);
    int*    bsum   = (int*)alloc(512 * 4);
    int*    ebase  = (int*)alloc((size_t)(NB + 1) * 4);
    int*    bcur   = (int*)alloc((size_t)(NB + 1) * 4);
    int*    binned = (int*)alloc((size_t)N_EDGES * 4);    // packed {ldst, src}
    int*    em     = (int*)alloc((size_t)ETOT * 4);       // src only
    float*  agg    = (float*)alloc((size_t)N * HIDDEN * 4);
    __half* x16    = (__half*)alloc((size_t)N * IN_DIM * 2);
    __half* h16    = (__half*)alloc((size_t)N * HIDDEN * 2);
    (void)ws_size;

    const int gN = (N + 255) / 256;          // 391
    const int gE = (E + 255) / 256;          // 6250
    const int gAgg = (N + 3) / 4;            // 25000 (4 nodes/block)
    const int gGemm = (N + 127) / 128;       // 782
    const int gCast = (N * IN_DIM / 8 + 255) / 256;

    // CSR build: node-level count+scan (proven cheap) + contention-free two-phase fill
    init_cnt_k<<<gN, 256, 0, stream>>>(cnt, N);
    count_k<<<gE, 256, 0, stream>>>(dstA, cnt, E);
    scan_block_k<<<gN, 256, 0, stream>>>(cnt, rowptr, bsum, dinv, N);
    scan_bsum_k<<<1, 512, 0, stream>>>(bsum, gN);
    scan_add_k<<<gN, 256, 0, stream>>>(rowptr, bsum, N, ETOT);
    init_ebase_k<<<1, 1024, 0, stream>>>(rowptr, ebase, bcur, E);
    binA_k<<<NBLK, 256, 0, stream>>>(srcA, dstA, bcur, binned, E);
    place_k<<<NB, 256, 0, stream>>>(binned, ebase, rowptr, em, N);
    cast16_k<<<gCast, 256, 0, stream>>>(x, x16, N * IN_DIM / 8);

    // layer 1: h16 = fp16(relu(Agg(x16) @ W1 + b1))   (aggregate in 64-dim)
    agg_k<64><<<gAgg, 256, 0, stream>>>(x16, rowptr, em, dinv, agg, N);
    gemm128_k<64, true, false, __half><<<gGemm, 256, 0, stream>>>(agg, W1, nullptr, b1, nullptr,
                                                                  h16, nullptr, N);

    // layer 2: h16 = fp16(relu(Agg(h16) @ W2 + b2))
    agg_k<128><<<gAgg, 256, 0, stream>>>(h16, rowptr, em, dinv, agg, N);
    gemm128_k<128, true, false, __half><<<gGemm, 256, 0, stream>>>(agg, W2, nullptr, b2, nullptr,
                                                                   h16, nullptr, N);

    // heads: aggregate once, ONE fused GEMM (cols 0..63 = mu, 64..127 = logvar), fp32 out
    agg_k<128><<<gAgg, 256, 0, stream>>>(h16, rowptr, em, dinv, agg, N);
    gemm128_k<128, false, true, float><<<gGemm, 256, 0, stream>>>(agg, Wmu, Wlv, bmu, blv,
                                                                  out, out + (size_t)N * Z_DIM, N);
}

// Round 3
// 552.466 us; speedup vs baseline: 2.2295x; 1.0329x over previous
//
#include <hip/hip_runtime.h>
#include <hip/hip_fp16.h>
#include <cstddef>

// Problem constants (match reference)
#define N_NODES 100000
#define N_EDGES 1600000
#define E_TOT   (N_EDGES + N_NODES)   // edges + self loops = 1,700,000
#define IN_DIM  64
#define HIDDEN  128
#define Z_DIM   64

// dst-buckets for locality-preserving fill
#define BN 128
#define NB ((N_NODES + BN - 1) / BN)   // 782
#define NBLK 256                        // chunk blocks for binA

// ---------------- CSR build ----------------

// per-node degree count: 1.6M fire-and-forget atomics over 100K addresses (proven cheap)
// cnt is zeroed by hipMemsetAsync; self-loop (+1) folded into scan_block_k.
__global__ __launch_bounds__(256) void count_k(const int* __restrict__ dst, int* cnt, int e) {
    int i = blockIdx.x * 256 + threadIdx.x;
    if (i < e) atomicAdd(&cnt[dst[i]], 1);
}

// block-level exclusive scan of (cnt+1) -> rowptr (+ per-block sums); emits dinv = rsqrt(deg)
__global__ __launch_bounds__(256) void scan_block_k(const int* __restrict__ cnt, int* __restrict__ rowptr,
                                                    int* __restrict__ bsum, float* __restrict__ dinv, int n) {
    __shared__ int s[256];
    int tid = threadIdx.x;
    int i = blockIdx.x * 256 + tid;
    int v = (i < n) ? cnt[i] + 1 : 0;         // +1 self loop
    if (i < n) dinv[i] = rsqrtf((float)v);
    s[tid] = v;
    __syncthreads();
#pragma unroll
    for (int off = 1; off < 256; off <<= 1) {
        int t = (tid >= off) ? s[tid - off] : 0;
        __syncthreads();
        s[tid] += t;
        __syncthreads();
    }
    if (i < n) rowptr[i] = s[tid] - v;        // exclusive within block
    if (tid == 255) bsum[blockIdx.x] = s[255];
}

__global__ __launch_bounds__(512) void scan_bsum_k(int* bsum, int nb) {
    __shared__ int s[512];
    int tid = threadIdx.x;
    int v = (tid < nb) ? bsum[tid] : 0;
    s[tid] = v;
    __syncthreads();
#pragma unroll
    for (int off = 1; off < 512; off <<= 1) {
        int t = (tid >= off) ? s[tid - off] : 0;
        __syncthreads();
        s[tid] += t;
        __syncthreads();
    }
    if (tid < nb) bsum[tid] = s[tid] - v;     // exclusive
}

// add block sums; also emit bucket edge-space bases: ebase[b] = rowptr[b*BN] - b*BN
__global__ __launch_bounds__(256) void scan_add_k(int* __restrict__ rowptr, const int* __restrict__ bsum,
                                                  int* __restrict__ ebase, int* __restrict__ bcur,
                                                  int n, int etot, int e) {
    int i = blockIdx.x * 256 + threadIdx.x;
    if (i < n) {
        int val = rowptr[i] + bsum[blockIdx.x];
        rowptr[i] = val;
        if ((i & (BN - 1)) == 0) {
            int b = i >> 7;
            int eb = val - b * BN;
            ebase[b] = eb;
            bcur[b] = eb;
        }
    }
    if (i == 0) { rowptr[n] = etot; ebase[NB] = e; }
}

// Phase A: chunked binning. LDS bucket-hist per block; ONE with-return global atomic per
// (block,bucket) (200K total, 256/addr — no contention stall); place chunk into
// bucket-contiguous binned[] via LDS cursors. Packed 4B: {local_dst(7b) << 17 | src(17b)}.
__global__ __launch_bounds__(256) void binA_k(const int* __restrict__ src, const int* __restrict__ dst,
                                              int* __restrict__ bcur, int* __restrict__ binned, int e) {
    __shared__ int hist[NB];
    __shared__ int cur[NB];
    int t = threadIdx.x;
    int ch = (e + gridDim.x - 1) / gridDim.x;
    int i0 = blockIdx.x * ch;
    int i1 = i0 + ch; if (i1 > e) i1 = e;

    for (int b = t; b < NB; b += 256) hist[b] = 0;
    __syncthreads();
    for (int i = i0 + t; i < i1; i += 256)
        atomicAdd(&hist[dst[i] >> 7], 1);
    __syncthreads();
    for (int b = t; b < NB; b += 256) {
        int h = hist[b];
        cur[b] = h ? atomicAdd(&bcur[b], h) : 0;
    }
    __syncthreads();
    for (int i = i0 + t; i < i1; i += 256) {
        int s = src[i], d = dst[i];
        int p = atomicAdd(&cur[d >> 7], 1);
        binned[p] = ((d & 127) << 17) | s;
    }
}

// Phase B: one block per bucket. Per-node LDS cursors seeded from rowptr; all em writes
// for the bucket's ~7KB region come from ONE CU -> full-line merge in its L2.
__global__ __launch_bounds__(256) void place_k(const int* __restrict__ binned, const int* __restrict__ ebase,
                                               const int* __restrict__ rowptr, int* __restrict__ em, int n) {
    __shared__ int cur[BN];
    int b = blockIdx.x, t = threadIdx.x;
    int n0 = b * BN;
    int nn = n - n0; if (nn > BN) nn = BN;
    if (t < nn) {
        int rp = rowptr[n0 + t];
        em[rp] = n0 + t;          // self loop first
        cur[t] = rp + 1;
    }
    __syncthreads();
    int e0 = ebase[b], e1 = ebase[b + 1];
    for (int i = e0 + t; i < e1; i += 256) {
        int pk = binned[i];
        int q = atomicAdd(&cur[pk >> 17], 1);
        em[q] = pk & 0x1FFFF;
    }
}

// cast fp32 -> fp16, 8 elems per thread (total must be divisible by 8)
__global__ __launch_bounds__(256) void cast16_k(const float* __restrict__ in, __half* __restrict__ out, int total8) {
    int i = blockIdx.x * 256 + threadIdx.x;
    if (i >= total8) return;
    const float4* in4 = (const float4*)in;
    float4 a = in4[2 * i], b = in4[2 * i + 1];
    __half2 h0 = __floats2half2_rn(a.x, a.y);
    __half2 h1 = __floats2half2_rn(a.z, a.w);
    __half2 h2 = __floats2half2_rn(b.x, b.y);
    __half2 h3 = __floats2half2_rn(b.z, b.w);
    uint4 pk = make_uint4(*(unsigned*)&h0, *(unsigned*)&h1, *(unsigned*)&h2, *(unsigned*)&h3);
    ((uint4*)out)[i] = pk;
}

// ---------------- Aggregation (gather): fp16 rows, fp32 accumulate ----------------
// One node per wave. Edge granule = SUBS*2 (8 for DIM=128, 16 for DIM=64) to cut tail
// waste (E[slots]/deg: 1.45->1.21 at D=128, 1.88->1.45 at D=64). Meta (em+dinv) for the
// next granule is prefetched during the current FMAs. fmaf(w, half2float(h), acc) lets
// the compiler emit v_fma_mix_f32 (no separate cvt). OUTT=half for hidden layers (halves
// intermediate traffic), float for the head.

template <int DIM, typename OUTT>
__global__ __launch_bounds__(256) void agg_k(const __half* __restrict__ H, const int* __restrict__ rowptr,
                                             const int* __restrict__ em, const float* __restrict__ dinv,
                                             OUTT* __restrict__ out, int n) {
    int node = (int)((blockIdx.x * 256 + threadIdx.x) >> 6);
    if (node >= n) return;
    int lane = threadIdx.x & 63;
    int beg = rowptr[node], end = rowptr[node + 1];
    float dn = dinv[node];
    const uint4* H4 = (const uint4*)H;       // 8 halves per uint4

    constexpr int RV   = DIM / 8;            // 16B-chunks per row (128->16, 64->8)
    constexpr int SUBS = 64 / RV;            // edge lanes-groups (4 or 8)
    constexpr int STEP = SUBS * 2;           // edges per iteration (8 or 16)
    int sub = lane / RV;
    int fl  = lane % RV;

    float acc[8];
#pragma unroll
    for (int q = 0; q < 8; q++) acc[q] = 0.f;

    // meta loader: edge slot j + SUBS*p + sub (clamped, weight 0 when OOB)
    auto meta = [&](int j, int p, int& s, float& w) {
        int idx = j + SUBS * p + sub;
        int ci  = idx < end ? idx : beg;
        int sv  = em[ci];
        s = sv;
        w = idx < end ? dinv[sv] * dn : 0.f;
    };

    int s0, s1; float w0, w1;
    meta(beg, 0, s0, w0);
    meta(beg, 1, s1, w1);
    int j = beg;
    while (true) {
        uint4 v0 = H4[(size_t)s0 * RV + fl];
        uint4 v1 = H4[(size_t)s1 * RV + fl];
        int jn = j + STEP;
        bool more = jn < end;                 // wave-uniform
        int ns0 = 0, ns1 = 0; float nw0 = 0.f, nw1 = 0.f;
        if (more) { meta(jn, 0, ns0, nw0); meta(jn, 1, ns1, nw1); }
        const __half* h0 = (const __half*)&v0;
        const __half* h1 = (const __half*)&v1;
#pragma unroll
        for (int q = 0; q < 8; q++) acc[q] = fmaf(w0, __half2float(h0[q]), acc[q]);
#pragma unroll
        for (int q = 0; q < 8; q++) acc[q] = fmaf(w1, __half2float(h1[q]), acc[q]);
        if (!more) break;
        j = jn; s0 = ns0; s1 = ns1; w0 = nw0; w1 = nw1;
    }

    // combine sub-groups: xor-reduce down to sub==0
#pragma unroll
    for (int off = 32; off >= RV; off >>= 1) {
#pragma unroll
        for (int q = 0; q < 8; q++) acc[q] += __shfl_xor(acc[q], off);
    }
    if (sub == 0) {
        if constexpr (sizeof(OUTT) == 2) {
            __half2 q0 = __floats2half2_rn(acc[0], acc[1]);
            __half2 q1 = __floats2half2_rn(acc[2], acc[3]);
            __half2 q2 = __floats2half2_rn(acc[4], acc[5]);
            __half2 q3 = __floats2half2_rn(acc[6], acc[7]);
            uint4 pk = make_uint4(*(unsigned*)&q0, *(unsigned*)&q1, *(unsigned*)&q2, *(unsigned*)&q3);
            *(uint4*)((__half*)out + (size_t)node * DIM + fl * 8) = pk;
        } else {
            float* op = (float*)out + (size_t)node * DIM + fl * 8;
            *(float4*)op = make_float4(acc[0], acc[1], acc[2], acc[3]);
            *(float4*)(op + 4) = make_float4(acc[4], acc[5], acc[6], acc[7]);
        }
    }
}

// ---------------- Dense layer: whole W in LDS, ONE barrier, A streamed from global --------
// Block = 256 threads, 128 nodes. fg=t&7 owns feats fg*4+32*j; mg=t>>3 owns rows mg*4+r.
// ATT=__half: A is fp16 (hidden-layer agg output); ATT=float: head path. OUTT=__half:
// emit fp16 rows for the next gather; OUTT=float: head output. DUAL: cols 0..63 -> Ca,
// 64..127 -> Cb.

template <int K, bool RELU, bool DUAL, typename ATT, typename OUTT>
__global__ __launch_bounds__(256, 3) void gemm128_k(const ATT* __restrict__ A,
                                                    const float* __restrict__ Wa, const float* __restrict__ Wb,
                                                    const float* __restrict__ ba, const float* __restrict__ bb,
                                                    OUTT* __restrict__ Ca, OUTT* __restrict__ Cb, int n) {
    constexpr int F  = 128;
    constexpr int NT = 128;          // nodes per block
    __shared__ __align__(16) float Ws[K * F];    // 32 KB (K=64) / 64 KB (K=128)

    int t  = threadIdx.x;
    int fg = t & 7;
    int mg = t >> 3;
    int m0 = blockIdx.x * NT;

    // stage whole W (K*F/4 float4, coalesced)
    for (int e = t; e < K * F / 4; e += 256) {
        float4 w;
        if (!DUAL) {
            w = ((const float4*)Wa)[e];
        } else {
            int r = e >> 5;              // k row
            int c = (e & 31) * 4;        // float col 0..127
            w = (c < 64) ? *(const float4*)&Wa[(size_t)r * 64 + c]
                         : *(const float4*)&Wb[(size_t)r * 64 + (c - 64)];
        }
        ((float4*)Ws)[e] = w;
    }
    __syncthreads();

    // row pointers (clamped; garbage rows computed but not stored)
    const ATT* Ap[4];
#pragma unroll
    for (int r = 0; r < 4; r++) {
        int row = m0 + mg * 4 + r;
        Ap[r] = A + (size_t)(row < n ? row : (n - 1)) * K;
    }

    float4 acc[4][4];                // [r][j]
#pragma unroll
    for (int r = 0; r < 4; r++)
#pragma unroll
        for (int j = 0; j < 4; j++) { acc[r][j].x = 0.f; acc[r][j].y = 0.f; acc[r][j].z = 0.f; acc[r][j].w = 0.f; }

    for (int k8 = 0; k8 < K; k8 += 8) {
        float a[4][8];
#pragma unroll
        for (int r = 0; r < 4; r++) {
            if constexpr (sizeof(ATT) == 2) {
                uint4 v = *(const uint4*)&Ap[r][k8];
                const __half* h = (const __half*)&v;
#pragma unroll
                for (int u = 0; u < 8; u++) a[r][u] = __half2float(h[u]);
            } else {
                float4 x0 = *(const float4*)&Ap[r][k8];
                float4 x1 = *(const float4*)&Ap[r][k8 + 4];
                a[r][0] = x0.x; a[r][1] = x0.y; a[r][2] = x0.z; a[r][3] = x0.w;
                a[r][4] = x1.x; a[r][5] = x1.y; a[r][6] = x1.z; a[r][7] = x1.w;
            }
        }
#pragma unroll
        for (int kk = 0; kk < 8; kk++) {
#pragma unroll
            for (int j = 0; j < 4; j++) {
                float4 w = ((const float4*)Ws)[(k8 + kk) * (F / 4) + fg + 8 * j];
                acc[0][j].x += a[0][kk] * w.x; acc[0][j].y += a[0][kk] * w.y;
                acc[0][j].z += a[0][kk] * w.z; acc[0][j].w += a[0][kk] * w.w;
                acc[1][j].x += a[1][kk] * w.x; acc[1][j].y += a[1][kk] * w.y;
                acc[1][j].z += a[1][kk] * w.z; acc[1][j].w += a[1][kk] * w.w;
                acc[2][j].x += a[2][kk] * w.x; acc[2][j].y += a[2][kk] * w.y;
                acc[2][j].z += a[2][kk] * w.z; acc[2][j].w += a[2][kk] * w.w;
                acc[3][j].x += a[3][kk] * w.x; acc[3][j].y += a[3][kk] * w.y;
                acc[3][j].z += a[3][kk] * w.z; acc[3][j].w += a[3][kk] * w.w;
            }
        }
    }

    // epilogue: bias + optional relu; DUAL splits cols 0..63 / 64..127
#pragma unroll
    for (int r = 0; r < 4; r++) {
        int node = m0 + mg * 4 + r;
        if (node >= n) break;
#pragma unroll
        for (int j = 0; j < 4; j++) {
            int f = fg * 4 + 32 * j;
            float4 v = acc[r][j];
            const float* bp;
            OUTT* cp;
            int fo;
            if (!DUAL) {
                bp = ba; cp = Ca + (size_t)node * F; fo = f;
            } else if (j < 2) {              // f < 64
                bp = ba; cp = Ca + (size_t)node * 64; fo = f;
            } else {
                bp = bb; cp = Cb + (size_t)node * 64; fo = f - 64;
            }
            v.x += bp[fo + 0]; v.y += bp[fo + 1]; v.z += bp[fo + 2]; v.w += bp[fo + 3];
            if (RELU) {
                v.x = fmaxf(v.x, 0.f); v.y = fmaxf(v.y, 0.f);
                v.z = fmaxf(v.z, 0.f); v.w = fmaxf(v.w, 0.f);
            }
            if constexpr (sizeof(OUTT) == 2) {
                __half2 p01 = __floats2half2_rn(v.x, v.y);
                __half2 p23 = __floats2half2_rn(v.z, v.w);
                uint2 pk = make_uint2(*(unsigned*)&p01, *(unsigned*)&p23);
                *(uint2*)&cp[fo] = pk;       // 8B fp16 store
            } else {
                *(float4*)&cp[fo] = v;
            }
        }
    }
}

// ---------------- launch ----------------

extern "C" void kernel_launch(void* const* d_in, const int* in_sizes, int n_in,
                              void* d_out, int out_size, void* d_ws, size_t ws_size,
                              hipStream_t stream) {
    const int N = N_NODES, E = N_EDGES, ETOT = E_TOT;

    const float* x    = (const float*)d_in[0];
    const int*   ei   = (const int*)d_in[1];
    const int*   srcA = ei;
    const int*   dstA = ei + E;
    const float* W1   = (const float*)d_in[2];
    const float* b1   = (const float*)d_in[3];
    const float* W2   = (const float*)d_in[4];
    const float* b2   = (const float*)d_in[5];
    const float* Wmu  = (const float*)d_in[6];
    const float* bmu  = (const float*)d_in[7];
    const float* Wlv  = (const float*)d_in[8];
    const float* blv  = (const float*)d_in[9];
    float* out = (float*)d_out;

    // workspace carve-out
    char* ws = (char*)d_ws;
    size_t o = 0;
    auto alloc = [&](size_t bytes) -> void* {
        o = (o + 255) & ~(size_t)255;
        void* p = ws + o;
        o += bytes;
        return p;
    };
    int*    cnt    = (int*)alloc((size_t)N * 4);
    int*    rowptr = (int*)alloc((size_t)(N + 1) * 4);
    float*  dinv   = (float*)alloc((size_t)N * 4);
    int*    bsum   = (int*)alloc(512 * 4);
    int*    ebase  = (int*)alloc((size_t)(NB + 1) * 4);
    int*    bcur   = (int*)alloc((size_t)(NB + 1) * 4);
    int*    em     = (int*)alloc((size_t)ETOT * 4);       // src only
    __half* aggh   = (__half*)alloc((size_t)N * HIDDEN * 2);  // hidden agg out (fp16)
    __half* h16    = (__half*)alloc((size_t)N * HIDDEN * 2);
    // overlapped region: [x16 12.8MB][binned 6.4MB][pad 32MB] reused as head fp32 agg out
    char*   Rg     = (char*)alloc((size_t)N * HIDDEN * 4);    // 51.2MB
    __half* x16    = (__half*)Rg;                              // first 12.8MB
    int*    binned = (int*)(Rg + (size_t)N * IN_DIM * 2);      // next 6.4MB
    float*  aggf   = (float*)Rg;                               // alias: live only at head
    (void)ws_size;

    const int gN = (N + 255) / 256;          // 391
    const int gE = (E + 255) / 256;          // 6250
    const int gAgg = (N + 3) / 4;            // 25000 (4 nodes/block)
    const int gGemm = (N + 127) / 128;       // 782
    const int gCast = (N * IN_DIM / 8 + 255) / 256;

    // CSR build: node-level count+scan + contention-free two-phase fill
    hipMemsetAsync(cnt, 0, (size_t)N * 4, stream);
    count_k<<<gE, 256, 0, stream>>>(dstA, cnt, E);
    scan_block_k<<<gN, 256, 0, stream>>>(cnt, rowptr, bsum, dinv, N);
    scan_bsum_k<<<1, 512, 0, stream>>>(bsum, gN);
    scan_add_k<<<gN, 256, 0, stream>>>(rowptr, bsum, ebase, bcur, N, ETOT, E);
    binA_k<<<NBLK, 256, 0, stream>>>(srcA, dstA, bcur, binned, E);
    place_k<<<NB, 256, 0, stream>>>(binned, ebase, rowptr, em, N);
    cast16_k<<<gCast, 256, 0, stream>>>(x, x16, N * IN_DIM / 8);

    // layer 1: h16 = fp16(relu(Agg(x16) @ W1 + b1))   (aggregate in 64-dim, fp16 out)
    agg_k<64, __half><<<gAgg, 256, 0, stream>>>(x16, rowptr, em, dinv, aggh, N);
    gemm128_k<64, true, false, __half, __half><<<gGemm, 256, 0, stream>>>(aggh, W1, nullptr, b1, nullptr,
                                                                          h16, nullptr, N);

    // layer 2: h16 = fp16(relu(Agg(h16) @ W2 + b2))   (fp16 agg out)
    agg_k<128, __half><<<gAgg, 256, 0, stream>>>(h16, rowptr, em, dinv, aggh, N);
    gemm128_k<128, true, false, __half, __half><<<gGemm, 256, 0, stream>>>(aggh, W2, nullptr, b2, nullptr,
                                                                           h16, nullptr, N);

    // heads: aggregate once (fp32 out into aliased region; x16/binned dead by now),
    // ONE fused GEMM (cols 0..63 = mu, 64..127 = logvar), fp32 out
    agg_k<128, float><<<gAgg, 256, 0, stream>>>(h16, rowptr, em, dinv, aggf, N);
    gemm128_k<128, false, true, float, float><<<gGemm, 256, 0, stream>>>(aggf, Wmu, Wlv, bmu, blv,
                                                                         out, out + (size_t)N * Z_DIM, N);
}

// Round 4
// 455.583 us; speedup vs baseline: 2.7037x; 1.2127x over previous
//
#include <hip/hip_runtime.h>
#include <hip/hip_fp16.h>
#include <cstddef>

// Problem constants (match reference)
#define N_NODES 100000
#define N_EDGES 1600000
#define E_TOT   (N_EDGES + N_NODES)   // edges + self loops = 1,700,000
#define IN_DIM  64
#define HIDDEN  128
#define Z_DIM   64

// dst-buckets for locality-preserving fill
#define BN 128
#define NB ((N_NODES + BN - 1) / BN)   // 782
#define NBLK 256                        // chunk blocks for binA

using f16x8 = __attribute__((ext_vector_type(8))) _Float16;
using f32x4 = __attribute__((ext_vector_type(4))) float;

// ---------------- CSR build ----------------

// per-node degree count: 1.6M fire-and-forget atomics over 100K addresses (proven cheap)
__global__ __launch_bounds__(256) void count_k(const int* __restrict__ dst, int* cnt, int e) {
    int i = blockIdx.x * 256 + threadIdx.x;
    if (i < e) atomicAdd(&cnt[dst[i]], 1);
}

// block-level exclusive scan of (cnt+1) -> rowptr (+ per-block sums); emits dinv = rsqrt(deg)
__global__ __launch_bounds__(256) void scan_block_k(const int* __restrict__ cnt, int* __restrict__ rowptr,
                                                    int* __restrict__ bsum, float* __restrict__ dinv, int n) {
    __shared__ int s[256];
    int tid = threadIdx.x;
    int i = blockIdx.x * 256 + tid;
    int v = (i < n) ? cnt[i] + 1 : 0;         // +1 self loop
    if (i < n) dinv[i] = rsqrtf((float)v);
    s[tid] = v;
    __syncthreads();
#pragma unroll
    for (int off = 1; off < 256; off <<= 1) {
        int t = (tid >= off) ? s[tid - off] : 0;
        __syncthreads();
        s[tid] += t;
        __syncthreads();
    }
    if (i < n) rowptr[i] = s[tid] - v;        // exclusive within block
    if (tid == 255) bsum[blockIdx.x] = s[255];
}

__global__ __launch_bounds__(512) void scan_bsum_k(int* bsum, int nb) {
    __shared__ int s[512];
    int tid = threadIdx.x;
    int v = (tid < nb) ? bsum[tid] : 0;
    s[tid] = v;
    __syncthreads();
#pragma unroll
    for (int off = 1; off < 512; off <<= 1) {
        int t = (tid >= off) ? s[tid - off] : 0;
        __syncthreads();
        s[tid] += t;
        __syncthreads();
    }
    if (tid < nb) bsum[tid] = s[tid] - v;     // exclusive
}

// add block sums; also emit bucket edge-space bases: ebase[b] = rowptr[b*BN] - b*BN
__global__ __launch_bounds__(256) void scan_add_k(int* __restrict__ rowptr, const int* __restrict__ bsum,
                                                  int* __restrict__ ebase, int* __restrict__ bcur,
                                                  int n, int etot, int e) {
    int i = blockIdx.x * 256 + threadIdx.x;
    if (i < n) {
        int val = rowptr[i] + bsum[blockIdx.x];
        rowptr[i] = val;
        if ((i & (BN - 1)) == 0) {
            int b = i >> 7;
            int eb = val - b * BN;
            ebase[b] = eb;
            bcur[b] = eb;
        }
    }
    if (i == 0) { rowptr[n] = etot; ebase[NB] = e; }
}

// Phase A: chunked binning. LDS bucket-hist per block; ONE with-return global atomic per
// (block,bucket) (200K total — no contention stall); place chunk into bucket-contiguous
// binned[] via LDS cursors. Packed 4B: {local_dst(7b) << 17 | src(17b)}.
__global__ __launch_bounds__(256) void binA_k(const int* __restrict__ src, const int* __restrict__ dst,
                                              int* __restrict__ bcur, int* __restrict__ binned, int e) {
    __shared__ int hist[NB];
    __shared__ int cur[NB];
    int t = threadIdx.x;
    int ch = (e + gridDim.x - 1) / gridDim.x;
    int i0 = blockIdx.x * ch;
    int i1 = i0 + ch; if (i1 > e) i1 = e;

    for (int b = t; b < NB; b += 256) hist[b] = 0;
    __syncthreads();
    for (int i = i0 + t; i < i1; i += 256)
        atomicAdd(&hist[dst[i] >> 7], 1);
    __syncthreads();
    for (int b = t; b < NB; b += 256) {
        int h = hist[b];
        cur[b] = h ? atomicAdd(&bcur[b], h) : 0;
    }
    __syncthreads();
    for (int i = i0 + t; i < i1; i += 256) {
        int s = src[i], d = dst[i];
        int p = atomicAdd(&cur[d >> 7], 1);
        binned[p] = ((d & 127) << 17) | s;
    }
}

// Phase B: one block per bucket. Per-node LDS cursors seeded from rowptr; all em writes
// for the bucket's ~7KB region come from ONE CU -> full-line merge in its L2.
__global__ __launch_bounds__(256) void place_k(const int* __restrict__ binned, const int* __restrict__ ebase,
                                               const int* __restrict__ rowptr, int* __restrict__ em, int n) {
    __shared__ int cur[BN];
    int b = blockIdx.x, t = threadIdx.x;
    int n0 = b * BN;
    int nn = n - n0; if (nn > BN) nn = BN;
    if (t < nn) {
        int rp = rowptr[n0 + t];
        em[rp] = n0 + t;          // self loop first
        cur[t] = rp + 1;
    }
    __syncthreads();
    int e0 = ebase[b], e1 = ebase[b + 1];
    for (int i = e0 + t; i < e1; i += 256) {
        int pk = binned[i];
        int q = atomicAdd(&cur[pk >> 17], 1);
        em[q] = pk & 0x1FFFF;
    }
}

// cast fp32 -> fp16, 8 elems per thread (total must be divisible by 8)
__global__ __launch_bounds__(256) void cast16_k(const float* __restrict__ in, __half* __restrict__ out, int total8) {
    int i = blockIdx.x * 256 + threadIdx.x;
    if (i >= total8) return;
    const float4* in4 = (const float4*)in;
    float4 a = in4[2 * i], b = in4[2 * i + 1];
    __half2 h0 = __floats2half2_rn(a.x, a.y);
    __half2 h1 = __floats2half2_rn(a.z, a.w);
    __half2 h2 = __floats2half2_rn(b.x, b.y);
    __half2 h3 = __floats2half2_rn(b.z, b.w);
    uint4 pk = make_uint4(*(unsigned*)&h0, *(unsigned*)&h1, *(unsigned*)&h2, *(unsigned*)&h3);
    ((uint4*)out)[i] = pk;
}

// one-time W prep: transpose + fp16 cast. W1t[col][k] (128x64), W2t (128x128),
// Wht (128x128: col<64 <- Wmu, col>=64 <- Wlv). Total 40960 elems — trivial.
__global__ __launch_bounds__(256) void wprep_k(const float* __restrict__ W1, const float* __restrict__ W2,
                                               const float* __restrict__ Wmu, const float* __restrict__ Wlv,
                                               __half* __restrict__ W1t, __half* __restrict__ W2t,
                                               __half* __restrict__ Wht) {
    int i = blockIdx.x * 256 + threadIdx.x;
    if (i < 128 * 64) {
        int col = i >> 6, k = i & 63;
        W1t[i] = __float2half(W1[k * 128 + col]);
    }
    int j = i - 128 * 64;
    if (j >= 0 && j < 128 * 128) {
        int col = j >> 7, k = j & 127;
        W2t[j] = __float2half(W2[k * 128 + col]);
    }
    int m = i - 128 * 64 - 128 * 128;
    if (m >= 0 && m < 128 * 128) {
        int col = m >> 7, k = m & 127;
        Wht[m] = __float2half(col < 64 ? Wmu[k * 64 + col] : Wlv[k * 64 + (col - 64)]);
    }
}

// ---------------- Aggregation (gather): fp16 rows, fp32 accumulate ----------------
// One node per wave; granule SUBS*2 edges; meta prefetched one granule ahead.

template <int DIM>
__global__ __launch_bounds__(256) void agg_k(const __half* __restrict__ H, const int* __restrict__ rowptr,
                                             const int* __restrict__ em, const float* __restrict__ dinv,
                                             __half* __restrict__ out, int n) {
    int node = (int)((blockIdx.x * 256 + threadIdx.x) >> 6);
    if (node >= n) return;
    int lane = threadIdx.x & 63;
    int beg = rowptr[node], end = rowptr[node + 1];
    float dn = dinv[node];
    const uint4* H4 = (const uint4*)H;

    constexpr int RV   = DIM / 8;
    constexpr int SUBS = 64 / RV;
    constexpr int STEP = SUBS * 2;
    int sub = lane / RV;
    int fl  = lane % RV;

    float acc[8];
#pragma unroll
    for (int q = 0; q < 8; q++) acc[q] = 0.f;

    auto meta = [&](int j, int p, int& s, float& w) {
        int idx = j + SUBS * p + sub;
        int ci  = idx < end ? idx : beg;
        int sv  = em[ci];
        s = sv;
        w = idx < end ? dinv[sv] * dn : 0.f;
    };

    int s0, s1; float w0, w1;
    meta(beg, 0, s0, w0);
    meta(beg, 1, s1, w1);
    int j = beg;
    while (true) {
        uint4 v0 = H4[(size_t)s0 * RV + fl];
        uint4 v1 = H4[(size_t)s1 * RV + fl];
        int jn = j + STEP;
        bool more = jn < end;
        int ns0 = 0, ns1 = 0; float nw0 = 0.f, nw1 = 0.f;
        if (more) { meta(jn, 0, ns0, nw0); meta(jn, 1, ns1, nw1); }
        const __half* h0 = (const __half*)&v0;
        const __half* h1 = (const __half*)&v1;
#pragma unroll
        for (int q = 0; q < 8; q++) acc[q] = fmaf(w0, __half2float(h0[q]), acc[q]);
#pragma unroll
        for (int q = 0; q < 8; q++) acc[q] = fmaf(w1, __half2float(h1[q]), acc[q]);
        if (!more) break;
        j = jn; s0 = ns0; s1 = ns1; w0 = nw0; w1 = nw1;
    }

#pragma unroll
    for (int off = 32; off >= RV; off >>= 1) {
#pragma unroll
        for (int q = 0; q < 8; q++) acc[q] += __shfl_xor(acc[q], off);
    }
    if (sub == 0) {
        __half2 q0 = __floats2half2_rn(acc[0], acc[1]);
        __half2 q1 = __floats2half2_rn(acc[2], acc[3]);
        __half2 q2 = __floats2half2_rn(acc[4], acc[5]);
        __half2 q3 = __floats2half2_rn(acc[6], acc[7]);
        uint4 pk = make_uint4(*(unsigned*)&q0, *(unsigned*)&q1, *(unsigned*)&q2, *(unsigned*)&q3);
        *(uint4*)(out + (size_t)node * DIM + fl * 8) = pk;
    }
}

// Head aggregation: out = Agg(P) + bias, fp32 direct to d_out (mu | logvar).
// Uses linearity: Agg(h)@W + b == Agg(h@W) + b, so P = h@[Wmu|Wlv] was computed first.
__global__ __launch_bounds__(256) void agg_head_k(const __half* __restrict__ P, const int* __restrict__ rowptr,
                                                  const int* __restrict__ em, const float* __restrict__ dinv,
                                                  const float* __restrict__ bmu, const float* __restrict__ blv,
                                                  float* __restrict__ mu, float* __restrict__ lv, int n) {
    int node = (int)((blockIdx.x * 256 + threadIdx.x) >> 6);
    if (node >= n) return;
    int lane = threadIdx.x & 63;
    int beg = rowptr[node], end = rowptr[node + 1];
    float dn = dinv[node];
    const uint4* H4 = (const uint4*)P;

    constexpr int RV = 16, SUBS = 4, STEP = 8;
    int sub = lane / RV;
    int fl  = lane % RV;

    float acc[8];
#pragma unroll
    for (int q = 0; q < 8; q++) acc[q] = 0.f;

    auto meta = [&](int j, int p, int& s, float& w) {
        int idx = j + SUBS * p + sub;
        int ci  = idx < end ? idx : beg;
        int sv  = em[ci];
        s = sv;
        w = idx < end ? dinv[sv] * dn : 0.f;
    };

    int s0, s1; float w0, w1;
    meta(beg, 0, s0, w0);
    meta(beg, 1, s1, w1);
    int j = beg;
    while (true) {
        uint4 v0 = H4[(size_t)s0 * RV + fl];
        uint4 v1 = H4[(size_t)s1 * RV + fl];
        int jn = j + STEP;
        bool more = jn < end;
        int ns0 = 0, ns1 = 0; float nw0 = 0.f, nw1 = 0.f;
        if (more) { meta(jn, 0, ns0, nw0); meta(jn, 1, ns1, nw1); }
        const __half* h0 = (const __half*)&v0;
        const __half* h1 = (const __half*)&v1;
#pragma unroll
        for (int q = 0; q < 8; q++) acc[q] = fmaf(w0, __half2float(h0[q]), acc[q]);
#pragma unroll
        for (int q = 0; q < 8; q++) acc[q] = fmaf(w1, __half2float(h1[q]), acc[q]);
        if (!more) break;
        j = jn; s0 = ns0; s1 = ns1; w0 = nw0; w1 = nw1;
    }

#pragma unroll
    for (int off = 32; off >= RV; off >>= 1) {
#pragma unroll
        for (int q = 0; q < 8; q++) acc[q] += __shfl_xor(acc[q], off);
    }
    if (sub == 0) {
        // feats fl*8 .. fl*8+7; fl<8 -> mu, fl>=8 -> logvar (chunks don't straddle 64)
        const float* bp = (fl < 8) ? (bmu + fl * 8) : (blv + (fl - 8) * 8);
#pragma unroll
        for (int q = 0; q < 8; q++) acc[q] += bp[q];
        float* op = (fl < 8) ? (mu + (size_t)node * 64 + fl * 8)
                             : (lv + (size_t)node * 64 + (fl - 8) * 8);
        *(float4*)op = make_float4(acc[0], acc[1], acc[2], acc[3]);
        *(float4*)(op + 4) = make_float4(acc[4], acc[5], acc[6], acc[7]);
    }
}

// ---------------- MFMA GEMM: C[n x 128] = A[n x K] @ W[K x 128] (+bias, relu) ----------
// 256 thr = 4 waves, 64 rows/block (wave w -> rows m0+16w..+15), 8 col-tiles per wave.
// W^T fp16 staged in LDS ([col][k], 16/32 KB) with XOR swizzle ^((col&7)<<4) to kill the
// 16-way ds_read_b128 bank conflict. A fragments loaded direct from global (16B/lane).
// mfma_f32_16x16x32_f16: a[e]=A[lane&15][(lane>>4)*8+e], b[e]=W[(lane>>4)*8+e][col],
// d[r]=C[(lane>>4)*4+r][col=lane&15] (per verified gfx950 layout).

template <int K, bool BR>
__global__ __launch_bounds__(256) void mgemm_k(const __half* __restrict__ A,
                                               const __half* __restrict__ Wt,   // [128][K] fp16
                                               const float* __restrict__ bias,
                                               __half* __restrict__ C, int n) {
    __shared__ __align__(16) __half Wl[128 * K];
    int t = threadIdx.x;

    // stage Wt -> LDS (16B chunks, XOR swizzle on write; reads use the same XOR)
    constexpr int CHUNKS = 128 * K / 8;     // 16B chunks
    const uint4* Wg = (const uint4*)Wt;
    for (int i = t; i < CHUNKS; i += 256) {
        int g = i * 16;
        int col = g / (2 * K);
        uint4 v = Wg[i];
        *(uint4*)((char*)Wl + (g ^ ((col & 7) << 4))) = v;
    }
    __syncthreads();

    int lane = t & 63, w = t >> 6;
    int colb = lane & 15;
    int kq = (lane >> 4) * 8;
    int m0 = blockIdx.x * 64 + w * 16;
    int rowA = m0 + colb; if (rowA >= n) rowA = n - 1;
    const __half* Arow = A + (size_t)rowA * K + kq;

    f32x4 acc[8];
#pragma unroll
    for (int c = 0; c < 8; c++) acc[c] = (f32x4){0.f, 0.f, 0.f, 0.f};

    const char* wb = (const char*)Wl;
    int swz = (colb & 7) << 4;
    int off0 = colb * (2 * K) + kq * 2;

#pragma unroll
    for (int k0 = 0; k0 < K; k0 += 32) {
        f16x8 a = *(const f16x8*)(Arow + k0);
#pragma unroll
        for (int c = 0; c < 8; c++) {
            f16x8 b = *(const f16x8*)(wb + ((off0 + c * (32 * K) + k0 * 2) ^ swz));
            acc[c] = __builtin_amdgcn_mfma_f32_16x16x32_f16(a, b, acc[c], 0, 0, 0);
        }
    }

    int rbase = m0 + (lane >> 4) * 4;
#pragma unroll
    for (int c = 0; c < 8; c++) {
        int col = c * 16 + colb;
        float bv = BR ? bias[col] : 0.f;
#pragma unroll
        for (int r = 0; r < 4; r++) {
            int row = rbase + r;
            if (row < n) {
                float v = acc[c][r] + bv;
                if (BR) v = fmaxf(v, 0.f);
                C[(size_t)row * 128 + col] = __float2half(v);
            }
        }
    }
}

// ---------------- launch ----------------

extern "C" void kernel_launch(void* const* d_in, const int* in_sizes, int n_in,
                              void* d_out, int out_size, void* d_ws, size_t ws_size,
                              hipStream_t stream) {
    const int N = N_NODES, E = N_EDGES, ETOT = E_TOT;

    const float* x    = (const float*)d_in[0];
    const int*   ei   = (const int*)d_in[1];
    const int*   srcA = ei;
    const int*   dstA = ei + E;
    const float* W1   = (const float*)d_in[2];
    const float* b1   = (const float*)d_in[3];
    const float* W2   = (const float*)d_in[4];
    const float* b2   = (const float*)d_in[5];
    const float* Wmu  = (const float*)d_in[6];
    const float* bmu  = (const float*)d_in[7];
    const float* Wlv  = (const float*)d_in[8];
    const float* blv  = (const float*)d_in[9];
    float* out = (float*)d_out;

    // workspace carve-out
    char* ws = (char*)d_ws;
    size_t o = 0;
    auto alloc = [&](size_t bytes) -> void* {
        o = (o + 255) & ~(size_t)255;
        void* p = ws + o;
        o += bytes;
        return p;
    };
    int*    cnt    = (int*)alloc((size_t)N * 4);
    int*    rowptr = (int*)alloc((size_t)(N + 1) * 4);
    float*  dinv   = (float*)alloc((size_t)N * 4);
    int*    bsum   = (int*)alloc(512 * 4);
    int*    ebase  = (int*)alloc((size_t)(NB + 1) * 4);
    int*    bcur   = (int*)alloc((size_t)(NB + 1) * 4);
    int*    em     = (int*)alloc((size_t)ETOT * 4);           // src only
    int*    binned = (int*)alloc((size_t)E * 4);
    __half* x16    = (__half*)alloc((size_t)N * IN_DIM * 2);
    __half* B1     = (__half*)alloc((size_t)N * HIDDEN * 2);  // agg out / P
    __half* B2     = (__half*)alloc((size_t)N * HIDDEN * 2);  // gemm out
    __half* W1t    = (__half*)alloc(128 * 64 * 2);
    __half* W2t    = (__half*)alloc(128 * 128 * 2);
    __half* Wht    = (__half*)alloc(128 * 128 * 2);
    (void)ws_size;

    const int gN = (N + 255) / 256;          // 391
    const int gE = (E + 255) / 256;          // 6250
    const int gAgg = (N + 3) / 4;            // 25000 (4 nodes/block)
    const int gMg  = (N + 63) / 64;          // 1563 (64 rows/block)
    const int gCast = (N * IN_DIM / 8 + 255) / 256;

    // CSR build: node-level count+scan + contention-free two-phase fill; W prep; x cast
    hipMemsetAsync(cnt, 0, (size_t)N * 4, stream);
    count_k<<<gE, 256, 0, stream>>>(dstA, cnt, E);
    scan_block_k<<<gN, 256, 0, stream>>>(cnt, rowptr, bsum, dinv, N);
    scan_bsum_k<<<1, 512, 0, stream>>>(bsum, gN);
    scan_add_k<<<gN, 256, 0, stream>>>(rowptr, bsum, ebase, bcur, N, ETOT, E);
    binA_k<<<NBLK, 256, 0, stream>>>(srcA, dstA, bcur, binned, E);
    place_k<<<NB, 256, 0, stream>>>(binned, ebase, rowptr, em, N);
    wprep_k<<<160, 256, 0, stream>>>(W1, W2, Wmu, Wlv, W1t, W2t, Wht);
    cast16_k<<<gCast, 256, 0, stream>>>(x, x16, N * IN_DIM / 8);

    // layer 1: h = relu(Agg(x16) @ W1 + b1)        [agg 64-dim -> MFMA K=64]
    agg_k<64><<<gAgg, 256, 0, stream>>>(x16, rowptr, em, dinv, B1, N);
    mgemm_k<64, true><<<gMg, 256, 0, stream>>>(B1, W1t, b1, B2, N);

    // layer 2: h = relu(Agg(h) @ W2 + b2)          [agg 128-dim -> MFMA K=128]
    agg_k<128><<<gAgg, 256, 0, stream>>>(B2, rowptr, em, dinv, B1, N);
    mgemm_k<128, true><<<gMg, 256, 0, stream>>>(B1, W2t, b2, B2, N);

    // heads via linearity: P = h @ [Wmu|Wlv] (fp16), then out = Agg(P) + bias (fp32)
    mgemm_k<128, false><<<gMg, 256, 0, stream>>>(B2, Wht, nullptr, B1, N);
    agg_head_k<<<gAgg, 256, 0, stream>>>(B1, rowptr, em, dinv, bmu, blv,
                                         out, out + (size_t)N * Z_DIM, N);
}

// Round 5
// 426.623 us; speedup vs baseline: 2.8872x; 1.0679x over previous
//
#include <hip/hip_runtime.h>
#include <hip/hip_fp16.h>
#include <cstddef>

// Problem constants (match reference)
#define N_NODES 100000
#define N_EDGES 1600000
#define E_TOT   (N_EDGES + N_NODES)   // edges + self loops = 1,700,000
#define IN_DIM  64
#define HIDDEN  128
#define Z_DIM   64

// dst-buckets for locality-preserving fill
#define BN 128
#define NB ((N_NODES + BN - 1) / BN)   // 782
#define NBLK 256                        // chunk blocks for binA

using f16x8 = __attribute__((ext_vector_type(8))) _Float16;
using f32x4 = __attribute__((ext_vector_type(4))) float;

// ---------------- CSR build ----------------

// per-node degree count: 1.6M fire-and-forget atomics over 100K addresses (proven cheap)
__global__ __launch_bounds__(256) void count_k(const int* __restrict__ dst, int* cnt, int e) {
    int i = blockIdx.x * 256 + threadIdx.x;
    if (i < e) atomicAdd(&cnt[dst[i]], 1);
}

// block-level exclusive scan of (cnt+1) -> rowptr (+ per-block sums); emits dinv = rsqrt(deg)
__global__ __launch_bounds__(256) void scan_block_k(const int* __restrict__ cnt, int* __restrict__ rowptr,
                                                    int* __restrict__ bsum, float* __restrict__ dinv, int n) {
    __shared__ int s[256];
    int tid = threadIdx.x;
    int i = blockIdx.x * 256 + tid;
    int v = (i < n) ? cnt[i] + 1 : 0;         // +1 self loop
    if (i < n) dinv[i] = rsqrtf((float)v);
    s[tid] = v;
    __syncthreads();
#pragma unroll
    for (int off = 1; off < 256; off <<= 1) {
        int t = (tid >= off) ? s[tid - off] : 0;
        __syncthreads();
        s[tid] += t;
        __syncthreads();
    }
    if (i < n) rowptr[i] = s[tid] - v;        // exclusive within block
    if (tid == 255) bsum[blockIdx.x] = s[255];
}

__global__ __launch_bounds__(512) void scan_bsum_k(int* bsum, int nb) {
    __shared__ int s[512];
    int tid = threadIdx.x;
    int v = (tid < nb) ? bsum[tid] : 0;
    s[tid] = v;
    __syncthreads();
#pragma unroll
    for (int off = 1; off < 512; off <<= 1) {
        int t = (tid >= off) ? s[tid - off] : 0;
        __syncthreads();
        s[tid] += t;
        __syncthreads();
    }
    if (tid < nb) bsum[tid] = s[tid] - v;     // exclusive
}

// add block sums; also emit bucket edge-space bases: ebase[b] = rowptr[b*BN] - b*BN
__global__ __launch_bounds__(256) void scan_add_k(int* __restrict__ rowptr, const int* __restrict__ bsum,
                                                  int* __restrict__ ebase, int* __restrict__ bcur,
                                                  int n, int etot, int e) {
    int i = blockIdx.x * 256 + threadIdx.x;
    if (i < n) {
        int val = rowptr[i] + bsum[blockIdx.x];
        rowptr[i] = val;
        if ((i & (BN - 1)) == 0) {
            int b = i >> 7;
            int eb = val - b * BN;
            ebase[b] = eb;
            bcur[b] = eb;
        }
    }
    if (i == 0) { rowptr[n] = etot; ebase[NB] = e; }
}

// Phase A: chunked binning. LDS bucket-hist per block; ONE with-return global atomic per
// (block,bucket) (200K total — no contention stall); place chunk into bucket-contiguous
// binned[] via LDS cursors. Packed 4B: {local_dst(7b) << 17 | src(17b)}.
__global__ __launch_bounds__(256) void binA_k(const int* __restrict__ src, const int* __restrict__ dst,
                                              int* __restrict__ bcur, int* __restrict__ binned, int e) {
    __shared__ int hist[NB];
    __shared__ int cur[NB];
    int t = threadIdx.x;
    int ch = (e + gridDim.x - 1) / gridDim.x;
    int i0 = blockIdx.x * ch;
    int i1 = i0 + ch; if (i1 > e) i1 = e;

    for (int b = t; b < NB; b += 256) hist[b] = 0;
    __syncthreads();
    for (int i = i0 + t; i < i1; i += 256)
        atomicAdd(&hist[dst[i] >> 7], 1);
    __syncthreads();
    for (int b = t; b < NB; b += 256) {
        int h = hist[b];
        cur[b] = h ? atomicAdd(&bcur[b], h) : 0;
    }
    __syncthreads();
    for (int i = i0 + t; i < i1; i += 256) {
        int s = src[i], d = dst[i];
        int p = atomicAdd(&cur[d >> 7], 1);
        binned[p] = ((d & 127) << 17) | s;
    }
}

// Phase B: one block per bucket. Per-node LDS cursors seeded from rowptr; all em2 writes
// for the bucket's ~14KB region come from ONE CU -> full-line merge in its L2.
// Emits packed {src, normbits}: norm = dinv[src]*dinv[dst] (dst-dinv staged in LDS),
// removing the dependent dinv gather from the agg critical path.
__global__ __launch_bounds__(256) void place_k(const int* __restrict__ binned, const int* __restrict__ ebase,
                                               const int* __restrict__ rowptr, const float* __restrict__ dinv,
                                               int2* __restrict__ em, int n) {
    __shared__ int cur[BN];
    __shared__ float sdv[BN];
    int b = blockIdx.x, t = threadIdx.x;
    int n0 = b * BN;
    int nn = n - n0; if (nn > BN) nn = BN;
    if (t < nn) {
        int rp = rowptr[n0 + t];
        float dv = dinv[n0 + t];
        sdv[t] = dv;
        em[rp] = make_int2(n0 + t, __float_as_int(dv * dv));   // self loop first
        cur[t] = rp + 1;
    }
    __syncthreads();
    int e0 = ebase[b], e1 = ebase[b + 1];
    for (int i = e0 + t; i < e1; i += 256) {
        int pk = binned[i];
        int ld = pk >> 17, s = pk & 0x1FFFF;
        int q = atomicAdd(&cur[ld], 1);
        em[q] = make_int2(s, __float_as_int(dinv[s] * sdv[ld]));
    }
}

// cast fp32 -> fp16, 8 elems per thread (total must be divisible by 8)
__global__ __launch_bounds__(256) void cast16_k(const float* __restrict__ in, __half* __restrict__ out, int total8) {
    int i = blockIdx.x * 256 + threadIdx.x;
    if (i >= total8) return;
    const float4* in4 = (const float4*)in;
    float4 a = in4[2 * i], b = in4[2 * i + 1];
    __half2 h0 = __floats2half2_rn(a.x, a.y);
    __half2 h1 = __floats2half2_rn(a.z, a.w);
    __half2 h2 = __floats2half2_rn(b.x, b.y);
    __half2 h3 = __floats2half2_rn(b.z, b.w);
    uint4 pk = make_uint4(*(unsigned*)&h0, *(unsigned*)&h1, *(unsigned*)&h2, *(unsigned*)&h3);
    ((uint4*)out)[i] = pk;
}

// one-time W prep: transpose + fp16 cast. W1t[col][k] (128x64), W2t (128x128),
// Wht (128x128: col<64 <- Wmu, col>=64 <- Wlv). Total 40960 elems — trivial.
__global__ __launch_bounds__(256) void wprep_k(const float* __restrict__ W1, const float* __restrict__ W2,
                                               const float* __restrict__ Wmu, const float* __restrict__ Wlv,
                                               __half* __restrict__ W1t, __half* __restrict__ W2t,
                                               __half* __restrict__ Wht) {
    int i = blockIdx.x * 256 + threadIdx.x;
    if (i < 128 * 64) {
        int col = i >> 6, k = i & 63;
        W1t[i] = __float2half(W1[k * 128 + col]);
    }
    int j = i - 128 * 64;
    if (j >= 0 && j < 128 * 128) {
        int col = j >> 7, k = j & 127;
        W2t[j] = __float2half(W2[k * 128 + col]);
    }
    int m = i - 128 * 64 - 128 * 128;
    if (m >= 0 && m < 128 * 128) {
        int col = m >> 7, k = m & 127;
        Wht[m] = __float2half(col < 64 ? Wmu[k * 64 + col] : Wlv[k * 64 + (col - 64)]);
    }
}

// ---------------- Aggregation (gather): fp16 rows, fp32 accumulate ----------------
// One node per wave; granule = SUBS*2 edges. Depth-2 software pipeline: rows for granule
// g+1 are ISSUED before the FMAs of granule g (4 row loads + 2 meta loads in flight at
// the vmcnt wait). All loads clamp-indexed (weight-0 tail) -> zero branching in the loop.
// em entry is packed {src, normbits} so there is no dependent dinv gather in the chain.

template <int DIM>
__global__ __launch_bounds__(256) void agg_k(const __half* __restrict__ H, const int* __restrict__ rowptr,
                                             const int2* __restrict__ em, __half* __restrict__ out, int n) {
    int node = (int)((blockIdx.x * 256 + threadIdx.x) >> 6);
    if (node >= n) return;
    int lane = threadIdx.x & 63;
    int beg = rowptr[node], end = rowptr[node + 1];
    const uint4* H4 = (const uint4*)H;

    constexpr int RV   = DIM / 8;            // 16B-chunks per row (128->16, 64->8)
    constexpr int SUBS = 64 / RV;            // parallel edge slots (4 or 8)
    constexpr int STEP = SUBS * 2;           // edges per granule (8 or 16)
    int sub = lane / RV;
    int fl  = lane % RV;

    float acc[8];
#pragma unroll
    for (int q = 0; q < 8; q++) acc[q] = 0.f;

    auto meta = [&](int j, int p, int& s, float& w) {
        int idx = j + SUBS * p + sub;
        int ci  = idx < end ? idx : beg;
        int2 e  = em[ci];
        s = e.x;
        w = idx < end ? __int_as_float(e.y) : 0.f;
    };

    // prologue: granule 0 meta + rows, granule 1 meta
    int s0, s1, t0, t1; float w0, w1, u0, u1;
    meta(beg, 0, s0, w0);
    meta(beg, 1, s1, w1);
    uint4 v0 = H4[(size_t)s0 * RV + fl];
    uint4 v1 = H4[(size_t)s1 * RV + fl];
    int jn = beg + STEP;
    meta(jn, 0, t0, u0);
    meta(jn, 1, t1, u1);

    while (true) {
        // issue next granule's rows BEFORE consuming current
        uint4 p0 = H4[(size_t)t0 * RV + fl];
        uint4 p1 = H4[(size_t)t1 * RV + fl];
        int jnn = jn + STEP;
        int q0, q1; float x0, x1;
        meta(jnn, 0, q0, x0);
        meta(jnn, 1, q1, x1);

        const __half* h0 = (const __half*)&v0;
        const __half* h1 = (const __half*)&v1;
#pragma unroll
        for (int q = 0; q < 8; q++) acc[q] = fmaf(w0, __half2float(h0[q]), acc[q]);
#pragma unroll
        for (int q = 0; q < 8; q++) acc[q] = fmaf(w1, __half2float(h1[q]), acc[q]);

        if (jn >= end) break;
        v0 = p0; v1 = p1; w0 = u0; w1 = u1;
        t0 = q0; t1 = q1; u0 = x0; u1 = x1;
        jn = jnn;
    }

    // combine sub-groups: xor-reduce down to sub==0
#pragma unroll
    for (int off = 32; off >= RV; off >>= 1) {
#pragma unroll
        for (int q = 0; q < 8; q++) acc[q] += __shfl_xor(acc[q], off);
    }
    if (sub == 0) {
        __half2 q0 = __floats2half2_rn(acc[0], acc[1]);
        __half2 q1 = __floats2half2_rn(acc[2], acc[3]);
        __half2 q2 = __floats2half2_rn(acc[4], acc[5]);
        __half2 q3 = __floats2half2_rn(acc[6], acc[7]);
        uint4 pk = make_uint4(*(unsigned*)&q0, *(unsigned*)&q1, *(unsigned*)&q2, *(unsigned*)&q3);
        *(uint4*)(out + (size_t)node * DIM + fl * 8) = pk;
    }
}

// Head aggregation: out = Agg(P) + bias, fp32 direct to d_out (mu | logvar).
// Same depth-2 pipeline. Uses linearity: Agg(h)@W + b == Agg(h@W) + b.
__global__ __launch_bounds__(256) void agg_head_k(const __half* __restrict__ P, const int* __restrict__ rowptr,
                                                  const int2* __restrict__ em,
                                                  const float* __restrict__ bmu, const float* __restrict__ blv,
                                                  float* __restrict__ mu, float* __restrict__ lv, int n) {
    int node = (int)((blockIdx.x * 256 + threadIdx.x) >> 6);
    if (node >= n) return;
    int lane = threadIdx.x & 63;
    int beg = rowptr[node], end = rowptr[node + 1];
    const uint4* H4 = (const uint4*)P;

    constexpr int RV = 16, SUBS = 4, STEP = 8;
    int sub = lane / RV;
    int fl  = lane % RV;

    float acc[8];
#pragma unroll
    for (int q = 0; q < 8; q++) acc[q] = 0.f;

    auto meta = [&](int j, int p, int& s, float& w) {
        int idx = j + SUBS * p + sub;
        int ci  = idx < end ? idx : beg;
        int2 e  = em[ci];
        s = e.x;
        w = idx < end ? __int_as_float(e.y) : 0.f;
    };

    int s0, s1, t0, t1; float w0, w1, u0, u1;
    meta(beg, 0, s0, w0);
    meta(beg, 1, s1, w1);
    uint4 v0 = H4[(size_t)s0 * RV + fl];
    uint4 v1 = H4[(size_t)s1 * RV + fl];
    int jn = beg + STEP;
    meta(jn, 0, t0, u0);
    meta(jn, 1, t1, u1);

    while (true) {
        uint4 p0 = H4[(size_t)t0 * RV + fl];
        uint4 p1 = H4[(size_t)t1 * RV + fl];
        int jnn = jn + STEP;
        int q0, q1; float x0, x1;
        meta(jnn, 0, q0, x0);
        meta(jnn, 1, q1, x1);

        const __half* h0 = (const __half*)&v0;
        const __half* h1 = (const __half*)&v1;
#pragma unroll
        for (int q = 0; q < 8; q++) acc[q] = fmaf(w0, __half2float(h0[q]), acc[q]);
#pragma unroll
        for (int q = 0; q < 8; q++) acc[q] = fmaf(w1, __half2float(h1[q]), acc[q]);

        if (jn >= end) break;
        v0 = p0; v1 = p1; w0 = u0; w1 = u1;
        t0 = q0; t1 = q1; u0 = x0; u1 = x1;
        jn = jnn;
    }

#pragma unroll
    for (int off = 32; off >= RV; off >>= 1) {
#pragma unroll
        for (int q = 0; q < 8; q++) acc[q] += __shfl_xor(acc[q], off);
    }
    if (sub == 0) {
        // feats fl*8 .. fl*8+7; fl<8 -> mu, fl>=8 -> logvar (chunks don't straddle 64)
        const float* bp = (fl < 8) ? (bmu + fl * 8) : (blv + (fl - 8) * 8);
#pragma unroll
        for (int q = 0; q < 8; q++) acc[q] += bp[q];
        float* op = (fl < 8) ? (mu + (size_t)node * 64 + fl * 8)
                             : (lv + (size_t)node * 64 + (fl - 8) * 8);
        *(float4*)op = make_float4(acc[0], acc[1], acc[2], acc[3]);
        *(float4*)(op + 4) = make_float4(acc[4], acc[5], acc[6], acc[7]);
    }
}

// ---------------- MFMA GEMM: C[n x 128] = A[n x K] @ W[K x 128] (+bias, relu) ----------
// 256 thr = 4 waves, 64 rows/block (wave w -> rows m0+16w..+15), 8 col-tiles per wave.
// W^T fp16 staged in LDS ([col][k], 16/32 KB) with XOR swizzle ^((col&7)<<4) to kill the
// 16-way ds_read_b128 bank conflict. A fragments loaded direct from global (16B/lane).
// mfma_f32_16x16x32_f16: a[e]=A[lane&15][(lane>>4)*8+e], b[e]=W[(lane>>4)*8+e][col],
// d[r]=C[(lane>>4)*4+r][col=lane&15] (per verified gfx950 layout).

template <int K, bool BR>
__global__ __launch_bounds__(256) void mgemm_k(const __half* __restrict__ A,
                                               const __half* __restrict__ Wt,   // [128][K] fp16
                                               const float* __restrict__ bias,
                                               __half* __restrict__ C, int n) {
    __shared__ __align__(16) __half Wl[128 * K];
    int t = threadIdx.x;

    // stage Wt -> LDS (16B chunks, XOR swizzle on write; reads use the same XOR)
    constexpr int CHUNKS = 128 * K / 8;     // 16B chunks
    const uint4* Wg = (const uint4*)Wt;
    for (int i = t; i < CHUNKS; i += 256) {
        int g = i * 16;
        int col = g / (2 * K);
        uint4 v = Wg[i];
        *(uint4*)((char*)Wl + (g ^ ((col & 7) << 4))) = v;
    }
    __syncthreads();

    int lane = t & 63, w = t >> 6;
    int colb = lane & 15;
    int kq = (lane >> 4) * 8;
    int m0 = blockIdx.x * 64 + w * 16;
    int rowA = m0 + colb; if (rowA >= n) rowA = n - 1;
    const __half* Arow = A + (size_t)rowA * K + kq;

    f32x4 acc[8];
#pragma unroll
    for (int c = 0; c < 8; c++) acc[c] = (f32x4){0.f, 0.f, 0.f, 0.f};

    const char* wb = (const char*)Wl;
    int swz = (colb & 7) << 4;
    int off0 = colb * (2 * K) + kq * 2;

#pragma unroll
    for (int k0 = 0; k0 < K; k0 += 32) {
        f16x8 a = *(const f16x8*)(Arow + k0);
#pragma unroll
        for (int c = 0; c < 8; c++) {
            f16x8 b = *(const f16x8*)(wb + ((off0 + c * (32 * K) + k0 * 2) ^ swz));
            acc[c] = __builtin_amdgcn_mfma_f32_16x16x32_f16(a, b, acc[c], 0, 0, 0);
        }
    }

    int rbase = m0 + (lane >> 4) * 4;
#pragma unroll
    for (int c = 0; c < 8; c++) {
        int col = c * 16 + colb;
        float bv = BR ? bias[col] : 0.f;
#pragma unroll
        for (int r = 0; r < 4; r++) {
            int row = rbase + r;
            if (row < n) {
                float v = acc[c][r] + bv;
                if (BR) v = fmaxf(v, 0.f);
                C[(size_t)row * 128 + col] = __float2half(v);
            }
        }
    }
}

// ---------------- launch ----------------

extern "C" void kernel_launch(void* const* d_in, const int* in_sizes, int n_in,
                              void* d_out, int out_size, void* d_ws, size_t ws_size,
                              hipStream_t stream) {
    const int N = N_NODES, E = N_EDGES, ETOT = E_TOT;

    const float* x    = (const float*)d_in[0];
    const int*   ei   = (const int*)d_in[1];
    const int*   srcA = ei;
    const int*   dstA = ei + E;
    const float* W1   = (const float*)d_in[2];
    const float* b1   = (const float*)d_in[3];
    const float* W2   = (const float*)d_in[4];
    const float* b2   = (const float*)d_in[5];
    const float* Wmu  = (const float*)d_in[6];
    const float* bmu  = (const float*)d_in[7];
    const float* Wlv  = (const float*)d_in[8];
    const float* blv  = (const float*)d_in[9];
    float* out = (float*)d_out;

    // workspace carve-out
    char* ws = (char*)d_ws;
    size_t o = 0;
    auto alloc = [&](size_t bytes) -> void* {
        o = (o + 255) & ~(size_t)255;
        void* p = ws + o;
        o += bytes;
        return p;
    };
    int*    cnt    = (int*)alloc((size_t)N * 4);
    int*    rowptr = (int*)alloc((size_t)(N + 1) * 4);
    float*  dinv   = (float*)alloc((size_t)N * 4);
    int*    bsum   = (int*)alloc(512 * 4);
    int*    ebase  = (int*)alloc((size_t)(NB + 1) * 4);
    int*    bcur   = (int*)alloc((size_t)(NB + 1) * 4);
    int2*   em     = (int2*)alloc((size_t)ETOT * 8);          // packed {src, norm}
    int*    binned = (int*)alloc((size_t)E * 4);
    __half* x16    = (__half*)alloc((size_t)N * IN_DIM * 2);
    __half* B1     = (__half*)alloc((size_t)N * HIDDEN * 2);  // agg out / P
    __half* B2     = (__half*)alloc((size_t)N * HIDDEN * 2);  // gemm out
    __half* W1t    = (__half*)alloc(128 * 64 * 2);
    __half* W2t    = (__half*)alloc(128 * 128 * 2);
    __half* Wht    = (__half*)alloc(128 * 128 * 2);
    (void)ws_size;

    const int gN = (N + 255) / 256;          // 391
    const int gE = (E + 255) / 256;          // 6250
    const int gAgg = (N + 3) / 4;            // 25000 (4 nodes/block)
    const int gMg  = (N + 63) / 64;          // 1563 (64 rows/block)
    const int gCast = (N * IN_DIM / 8 + 255) / 256;

    // CSR build: node-level count+scan + contention-free two-phase fill; W prep; x cast
    hipMemsetAsync(cnt, 0, (size_t)N * 4, stream);
    count_k<<<gE, 256, 0, stream>>>(dstA, cnt, E);
    scan_block_k<<<gN, 256, 0, stream>>>(cnt, rowptr, bsum, dinv, N);
    scan_bsum_k<<<1, 512, 0, stream>>>(bsum, gN);
    scan_add_k<<<gN, 256, 0, stream>>>(rowptr, bsum, ebase, bcur, N, ETOT, E);
    binA_k<<<NBLK, 256, 0, stream>>>(srcA, dstA, bcur, binned, E);
    place_k<<<NB, 256, 0, stream>>>(binned, ebase, rowptr, dinv, em, N);
    wprep_k<<<160, 256, 0, stream>>>(W1, W2, Wmu, Wlv, W1t, W2t, Wht);
    cast16_k<<<gCast, 256, 0, stream>>>(x, x16, N * IN_DIM / 8);

    // layer 1: h = relu(Agg(x16) @ W1 + b1)        [agg 64-dim -> MFMA K=64]
    agg_k<64><<<gAgg, 256, 0, stream>>>(x16, rowptr, em, B1, N);
    mgemm_k<64, true><<<gMg, 256, 0, stream>>>(B1, W1t, b1, B2, N);

    // layer 2: h = relu(Agg(h) @ W2 + b2)          [agg 128-dim -> MFMA K=128]
    agg_k<128><<<gAgg, 256, 0, stream>>>(B2, rowptr, em, B1, N);
    mgemm_k<128, true><<<gMg, 256, 0, stream>>>(B1, W2t, b2, B2, N);

    // heads via linearity: P = h @ [Wmu|Wlv] (fp16), then out = Agg(P) + bias (fp32)
    mgemm_k<128, false><<<gMg, 256, 0, stream>>>(B2, Wht, nullptr, B1, N);
    agg_head_k<<<gAgg, 256, 0, stream>>>(B1, rowptr, em, bmu, blv,
                                         out, out + (size_t)N * Z_DIM, N);
}